// Round 2
// baseline (1331.615 us; speedup 1.0000x reference)
//
#include <hip/hip_runtime.h>
#include <cstdint>
#include <cstddef>

#define DEV __device__ __forceinline__

typedef __bf16 bf16x8 __attribute__((ext_vector_type(8)));
typedef float f32x4 __attribute__((ext_vector_type(4)));

static constexpr int D_MODEL = 2048;
static constexpr int D_FF    = 5632;
static constexpr int N_QKV   = 3072;   // 2048 q + 512 k + 512 v
static constexpr int SEQ     = 1024;
static constexpr int BATCH   = 2;
static constexpr int ROWS    = BATCH * SEQ;  // 2048
static constexpr int HEADS   = 16;
static constexpr int HD      = 128;

DEV uint16_t f2bf(float f) {
    uint32_t u = __float_as_uint(f);
    u += 0x7fffu + ((u >> 16) & 1u);   // RTNE
    return (uint16_t)(u >> 16);
}
DEV float bf2f(uint16_t h) { return __uint_as_float(((uint32_t)h) << 16); }
DEV uint32_t pack2bf(float a, float b) {
    return (uint32_t)f2bf(a) | ((uint32_t)f2bf(b) << 16);
}
DEV void split_bf(float v, uint16_t& hi, uint16_t& lo) {
    hi = f2bf(v);
    lo = f2bf(v - bf2f(hi));
}

// async global->LDS, 16B/lane; lds ptr must be wave-uniform (HW adds lane*16)
DEV void async_load16(const void* g, void* lds) {
    __builtin_amdgcn_global_load_lds(
        reinterpret_cast<__attribute__((address_space(1))) void*>(
            reinterpret_cast<uintptr_t>(g)),
        reinterpret_cast<__attribute__((address_space(3))) void*>(
            static_cast<uint32_t>(reinterpret_cast<uintptr_t>(lds))),
        16, 0, 0);
}

// ---------------------------------------------------------------------------
// Exact dequant: int32 q (|q|<=127, exact in bf16) -> bf16, NO scale.
// ---------------------------------------------------------------------------
__global__ __launch_bounds__(256)
void dequant_exact_kernel(const int* __restrict__ q, uint16_t* __restrict__ out, int n4)
{
    const int idx = blockIdx.x * 256 + threadIdx.x;
    if (idx >= n4) return;
    const int e = idx * 4;
    const int4 qv = *reinterpret_cast<const int4*>(&q[e]);
    uint2 pk;
    pk.x = pack2bf((float)qv.x, (float)qv.y);
    pk.y = pack2bf((float)qv.z, (float)qv.w);
    *reinterpret_cast<uint2*>(&out[e]) = pk;
}

__global__ __launch_bounds__(256)
void biascat_kernel(const float* __restrict__ bq, const float* __restrict__ bk,
                    const float* __restrict__ bv, float* __restrict__ out)
{
    const int i = blockIdx.x * 256 + threadIdx.x;
    if (i >= N_QKV) return;
    float v;
    if (i < 2048)      v = bq[i];
    else if (i < 2560) v = bk[i - 2048];
    else               v = bv[i - 2560];
    out[i] = v;
}

// ---------------------------------------------------------------------------
// RMSNorm (fp32 in) -> hi/lo bf16 pair. One row (2048) per block of 256.
// ---------------------------------------------------------------------------
__global__ __launch_bounds__(256)
void rmsnorm_kernel(const float* __restrict__ x, const float* __restrict__ wln,
                    uint16_t* __restrict__ ohi, uint16_t* __restrict__ olo)
{
    __shared__ float red[4];
    const int row = blockIdx.x;
    const int tid = threadIdx.x;
    const float* xr = x + (size_t)row * D_MODEL;
    const float4 v0 = *reinterpret_cast<const float4*>(&xr[tid * 8]);
    const float4 v1 = *reinterpret_cast<const float4*>(&xr[tid * 8 + 4]);
    float ss = v0.x*v0.x + v0.y*v0.y + v0.z*v0.z + v0.w*v0.w
             + v1.x*v1.x + v1.y*v1.y + v1.z*v1.z + v1.w*v1.w;
#pragma unroll
    for (int off = 32; off; off >>= 1) ss += __shfl_xor(ss, off);
    if ((tid & 63) == 0) red[tid >> 6] = ss;
    __syncthreads();
    const float rms = rsqrtf((red[0] + red[1] + red[2] + red[3]) * (1.0f / D_MODEL) + 1e-6f);
    const int cb = tid * 8;
    const size_t base = (size_t)row * D_MODEL + cb;
    const float vals[8] = {v0.x, v0.y, v0.z, v0.w, v1.x, v1.y, v1.z, v1.w};
#pragma unroll
    for (int k = 0; k < 8; k += 2) {
        uint16_t h0, l0, h1, l1;
        split_bf(vals[k] * rms * wln[cb + k], h0, l0);
        split_bf(vals[k + 1] * rms * wln[cb + k + 1], h1, l1);
        *reinterpret_cast<uint32_t*>(&ohi[base + k]) = (uint32_t)h0 | ((uint32_t)h1 << 16);
        *reinterpret_cast<uint32_t*>(&olo[base + k]) = (uint32_t)l0 | ((uint32_t)l1 << 16);
    }
}

// ---------------------------------------------------------------------------
// Quantized GEMM: C[m,n] = sum_g s[n,g] * sum_{k in g} (Ahi+Alo)[m,k]*Wint[n,k]
//   (+bias[n]) (+resid[m,n]).  A hi/lo bf16 (M,K), W exact-int bf16 (N,K).
// 128x128 tile, BK=64 (= 1 quant group), 4 waves 2x2, wave 4x4 MFMA 16x16x32.
// Per (i,j,group): 4 chained MFMAs into temp, then fp32 scale-accumulate.
// ---------------------------------------------------------------------------
template <bool SPLIT_OUT>
__global__ __launch_bounds__(256)
void gemm_qbt_kernel(const uint16_t* __restrict__ Ahi, const uint16_t* __restrict__ Alo,
                     const uint16_t* __restrict__ W, const float* __restrict__ scales,
                     const float* __restrict__ bias, const float* __restrict__ resid,
                     float* __restrict__ outf, uint16_t* __restrict__ ohi,
                     uint16_t* __restrict__ olo, int M, int N, int K)
{
    // layout: [ks(2)][row(128)][32 elems] per array (16 KB each)
    __shared__ uint16_t sAh[2 * 128 * 32];
    __shared__ uint16_t sAl[2 * 128 * 32];
    __shared__ uint16_t sB [2 * 128 * 32];

    const int tid  = threadIdx.x;
    const int lane = tid & 63;
    const int wv   = tid >> 6;
    const int wm   = wv >> 1;
    const int wn   = wv & 1;
    const int quad = lane >> 4;
    const int l16  = lane & 15;

    const int nBn = N >> 7;
    const int bm  = blockIdx.x / nBn;
    const int bn  = blockIdx.x - bm * nBn;
    const int m0  = bm << 7;
    const int n0  = bn << 7;

    f32x4 acc[4][4];
#pragma unroll
    for (int i = 0; i < 4; i++)
#pragma unroll
        for (int j = 0; j < 4; j++)
            acc[i][j] = (f32x4){0.f, 0.f, 0.f, 0.f};

    const uint16_t* Abh = Ahi + (size_t)m0 * K;
    const uint16_t* Abl = Alo + (size_t)m0 * K;
    const uint16_t* Wb  = W + (size_t)n0 * K;

    // per-lane scale row pointers (col fixed per lane per j)
    const int KG = K >> 6;
    const float* sp[4];
#pragma unroll
    for (int j = 0; j < 4; j++)
        sp[j] = scales + (size_t)(n0 + wn * 64 + j * 16 + l16) * KG;

    // staging: 1024 16B-chunks per array; chunk c -> LDS off c*16B;
    // ks=c>>9, row=(c>>2)&127, e=(c&3)*8; global = row*K + kt + ks*32 + e
    for (int kt = 0, g = 0; kt < K; kt += 64, g++) {
        __syncthreads();
#pragma unroll
        for (int p = 0; p < 4; p++) {
            const int cb = p * 256 + wv * 64;          // wave-uniform chunk base
            const int c  = cb + lane;
            const int ks = c >> 9, row = (c >> 2) & 127, e = (c & 3) * 8;
            const size_t goff = (size_t)row * K + kt + ks * 32 + e;
            async_load16(Abh + goff, &sAh[cb * 8]);
            async_load16(Abl + goff, &sAl[cb * 8]);
            async_load16(Wb  + goff, &sB [cb * 8]);
        }
        float sc[4];
#pragma unroll
        for (int j = 0; j < 4; j++) sc[j] = sp[j][g];
        __syncthreads();

        bf16x8 bfr[4][2];
#pragma unroll
        for (int j = 0; j < 4; j++)
#pragma unroll
            for (int ks = 0; ks < 2; ks++)
                bfr[j][ks] = *reinterpret_cast<const bf16x8*>(
                    &sB[ks * 4096 + (wn * 64 + j * 16 + l16) * 32 + quad * 8]);

#pragma unroll
        for (int i = 0; i < 4; i++) {
            const int ra = (wm * 64 + i * 16 + l16) * 32 + quad * 8;
            const bf16x8 ah0 = *reinterpret_cast<const bf16x8*>(&sAh[ra]);
            const bf16x8 ah1 = *reinterpret_cast<const bf16x8*>(&sAh[4096 + ra]);
            const bf16x8 al0 = *reinterpret_cast<const bf16x8*>(&sAl[ra]);
            const bf16x8 al1 = *reinterpret_cast<const bf16x8*>(&sAl[4096 + ra]);
#pragma unroll
            for (int j = 0; j < 4; j++) {
                f32x4 t = (f32x4){0.f, 0.f, 0.f, 0.f};
                t = __builtin_amdgcn_mfma_f32_16x16x32_bf16(al0, bfr[j][0], t, 0, 0, 0);
                t = __builtin_amdgcn_mfma_f32_16x16x32_bf16(al1, bfr[j][1], t, 0, 0, 0);
                t = __builtin_amdgcn_mfma_f32_16x16x32_bf16(ah0, bfr[j][0], t, 0, 0, 0);
                t = __builtin_amdgcn_mfma_f32_16x16x32_bf16(ah1, bfr[j][1], t, 0, 0, 0);
                acc[i][j] += sc[j] * t;
            }
        }
    }

    // epilogue: C row = quad*4+reg, col = lane&15 (m89-verified)
#pragma unroll
    for (int i = 0; i < 4; i++) {
        const int rowb = m0 + wm * 64 + i * 16 + quad * 4;
#pragma unroll
        for (int r = 0; r < 4; r++) {
            const size_t rr = (size_t)(rowb + r);
#pragma unroll
            for (int j = 0; j < 4; j++) {
                const int cc = n0 + wn * 64 + j * 16 + l16;
                float v = acc[i][j][r];
                if (bias)  v += bias[cc];
                if (resid) v += resid[rr * N + cc];
                if constexpr (SPLIT_OUT) {
                    uint16_t h, l;
                    split_bf(v, h, l);
                    ohi[rr * N + cc] = h;
                    olo[rr * N + cc] = l;
                } else {
                    outf[rr * N + cc] = v;
                }
            }
        }
    }
}

// ---------------------------------------------------------------------------
// RoPE in-place on qkv fp32: 20 "heads" (16 q + 4 k), pair (d, d+64).
// ---------------------------------------------------------------------------
__global__ __launch_bounds__(256)
void rope_kernel(float* __restrict__ qkv, const int* __restrict__ offp)
{
    const int idx = blockIdx.x * 256 + threadIdx.x;
    if (idx >= ROWS * 20 * 64) return;
    const int d   = idx & 63;
    const int hh  = (idx >> 6) % 20;
    const int row = idx / (64 * 20);
    const int s   = row & (SEQ - 1);
    const float pos  = (float)(s + *offp);
    const float freq = powf(1.0e6f, -(float)d * (1.0f / 64.0f));
    float sn, cs;
    sincosf(pos * freq, &sn, &cs);
    const size_t base = (size_t)row * N_QKV + hh * HD + d;
    const float x1 = qkv[base];
    const float x2 = qkv[base + 64];
    qkv[base]      = x1 * cs - x2 * sn;
    qkv[base + 64] = x2 * cs + x1 * sn;
}

// ---------------------------------------------------------------------------
// Causal GQA attention, fully fp32, online softmax. Block = 4 waves,
// 16 query rows (4/wave, 2 per half-wave), one (b,head). 32-key fp32 tiles
// (K padded 132, V padded 130). Output split hi/lo bf16 [row, h*128+d].
// ---------------------------------------------------------------------------
__global__ __launch_bounds__(256)
void attn_kernel(const float* __restrict__ qkv,
                 uint16_t* __restrict__ ohi, uint16_t* __restrict__ olo)
{
    __shared__ float sQ[16 * 128];
    __shared__ float sK[32 * 132];
    __shared__ float sV[32 * 130];
    __shared__ float sP[4][4][32];
    __shared__ float sAlf[4][4];
    __shared__ float sL[4][4];

    const int tid  = threadIdx.x;
    const int lane = tid & 63;
    const int wv   = tid >> 6;
    const int half = lane >> 5;
    const int kl   = lane & 31;

    const int bi  = blockIdx.x;
    const int sc  = bi & 63;
    const int h   = (bi >> 6) & 15;
    const int b   = bi >> 10;
    const int kvh = h >> 2;
    const int s0  = sc << 4;

    {   // Q rows, pre-scaled by 1/sqrt(128)
        const float qscale = 0.08838834764831845f;
#pragma unroll
        for (int p = 0; p < 2; p++) {
            const int q4 = p * 256 + tid;            // float4 index in [0,512)
            const int qr = q4 >> 5, qc = (q4 & 31) * 4;
            float4 v = *reinterpret_cast<const float4*>(
                &qkv[(size_t)(b * SEQ + s0 + qr) * N_QKV + h * HD + qc]);
            v.x *= qscale; v.y *= qscale; v.z *= qscale; v.w *= qscale;
            *reinterpret_cast<float4*>(&sQ[qr * 128 + qc]) = v;
        }
    }

    // this half-wave owns wave rows (half*2, half*2+1)
    const int ra = wv * 4 + half * 2;                // block-local row of dot0
    const int srow_a = s0 + ra;
    float m0v = -1e30f, m1v = -1e30f, l0v = 0.f, l1v = 0.f;
    float oa0[4], oa1[4];
#pragma unroll
    for (int r = 0; r < 4; r++) { oa0[r] = 0.f; oa1[r] = 0.f; }
    const int d0 = lane * 2;                         // PV dims owned by lane

    const int ntiles = ((s0 + 15) >> 5) + 1;
    for (int tt = 0; tt < ntiles; tt++) {
        const int t0 = tt << 5;
        __syncthreads();
#pragma unroll
        for (int p = 0; p < 4; p++) {
            const int q4 = p * 256 + tid;            // float4 index in [0,1024)
            const int tr = q4 >> 5, c4 = (q4 & 31) * 4;
            const size_t ga = (size_t)(b * SEQ + t0 + tr) * N_QKV + 2048 + kvh * HD + c4;
            *reinterpret_cast<float4*>(&sK[tr * 132 + c4]) =
                *reinterpret_cast<const float4*>(&qkv[ga]);
            *reinterpret_cast<float4*>(&sV[tr * 130 + c4]) =
                *reinterpret_cast<const float4*>(&qkv[ga + 512]);
        }
        __syncthreads();

        // QK^T: lane owns key t0+kl for its half's 2 rows
        float dot0 = 0.f, dot1 = 0.f;
        const float* kr = &sK[kl * 132];
#pragma unroll 4
        for (int d4 = 0; d4 < 32; d4++) {
            const float4 kv4 = *reinterpret_cast<const float4*>(&kr[d4 * 4]);
            const float4 qa = *reinterpret_cast<const float4*>(&sQ[ra * 128 + d4 * 4]);
            const float4 qb = *reinterpret_cast<const float4*>(&sQ[(ra + 1) * 128 + d4 * 4]);
            dot0 = fmaf(kv4.x, qa.x, dot0); dot0 = fmaf(kv4.y, qa.y, dot0);
            dot0 = fmaf(kv4.z, qa.z, dot0); dot0 = fmaf(kv4.w, qa.w, dot0);
            dot1 = fmaf(kv4.x, qb.x, dot1); dot1 = fmaf(kv4.y, qb.y, dot1);
            dot1 = fmaf(kv4.z, qb.z, dot1); dot1 = fmaf(kv4.w, qb.w, dot1);
        }
        const int key = t0 + kl;
        float s0v = (key <= srow_a)     ? dot0 : -1e30f;
        float s1v = (key <= srow_a + 1) ? dot1 : -1e30f;
        float mt0 = s0v, mt1 = s1v;
#pragma unroll
        for (int off = 16; off; off >>= 1) {
            mt0 = fmaxf(mt0, __shfl_xor(mt0, off));
            mt1 = fmaxf(mt1, __shfl_xor(mt1, off));
        }
        const float mn0 = fmaxf(m0v, mt0), mn1 = fmaxf(m1v, mt1);
        const float alf0 = __expf(m0v - mn0), alf1 = __expf(m1v - mn1);
        const float p0 = __expf(s0v - mn0), p1 = __expf(s1v - mn1);
        float ps0 = p0, ps1 = p1;
#pragma unroll
        for (int off = 16; off; off >>= 1) {
            ps0 += __shfl_xor(ps0, off);
            ps1 += __shfl_xor(ps1, off);
        }
        l0v = l0v * alf0 + ps0;  m0v = mn0;
        l1v = l1v * alf1 + ps1;  m1v = mn1;
        sP[wv][half * 2 + 0][kl] = p0;
        sP[wv][half * 2 + 1][kl] = p1;
        if (kl == 0) {
            sAlf[wv][half * 2 + 0] = alf0;
            sAlf[wv][half * 2 + 1] = alf1;
        }
        __syncthreads();

        // PV: lane owns dims (d0, d0+1) for all 4 wave rows
        float al[4];
#pragma unroll
        for (int r = 0; r < 4; r++) {
            al[r] = sAlf[wv][r];
            oa0[r] *= al[r];
            oa1[r] *= al[r];
        }
#pragma unroll 8
        for (int t = 0; t < 32; t++) {
            const float v0 = sV[t * 130 + d0];
            const float v1 = sV[t * 130 + d0 + 1];
#pragma unroll
            for (int r = 0; r < 4; r++) {
                const float p = sP[wv][r][t];
                oa0[r] = fmaf(p, v0, oa0[r]);
                oa1[r] = fmaf(p, v1, oa1[r]);
            }
        }
    }

    if (kl == 0) {
        sL[wv][half * 2 + 0] = l0v;
        sL[wv][half * 2 + 1] = l1v;
    }
    __syncthreads();
#pragma unroll
    for (int r = 0; r < 4; r++) {
        const float inv = 1.0f / sL[wv][r];
        const size_t off = (size_t)(b * SEQ + s0 + wv * 4 + r) * D_MODEL + h * HD + d0;
        const float o0 = oa0[r] * inv, o1 = oa1[r] * inv;
        uint16_t h0, l0, h1, l1;
        split_bf(o0, h0, l0);
        split_bf(o1, h1, l1);
        *reinterpret_cast<uint32_t*>(&ohi[off]) = (uint32_t)h0 | ((uint32_t)h1 << 16);
        *reinterpret_cast<uint32_t*>(&olo[off]) = (uint32_t)l0 | ((uint32_t)l1 << 16);
    }
}

// ---------------------------------------------------------------------------
// SwiGLU from hi/lo gubuf -> hi/lo act. Row stride 2*D_FF; up at +D_FF.
// ---------------------------------------------------------------------------
__global__ __launch_bounds__(256)
void silu_mul_kernel(const uint16_t* __restrict__ ghi, const uint16_t* __restrict__ glo,
                     uint16_t* __restrict__ ahi, uint16_t* __restrict__ alo)
{
    const int idx = blockIdx.x * 256 + threadIdx.x;
    const int n4 = ROWS * D_FF / 4;
    if (idx >= n4) return;
    const int e = idx * 4;
    const int m = e / D_FF;
    const int j = e - m * D_FF;
    const size_t gb = (size_t)m * (2 * D_FF) + j;
    const ushort4 gh = *reinterpret_cast<const ushort4*>(&ghi[gb]);
    const ushort4 gl = *reinterpret_cast<const ushort4*>(&glo[gb]);
    const ushort4 uh = *reinterpret_cast<const ushort4*>(&ghi[gb + D_FF]);
    const ushort4 ul = *reinterpret_cast<const ushort4*>(&glo[gb + D_FF]);
    const float gv[4] = {bf2f(gh.x) + bf2f(gl.x), bf2f(gh.y) + bf2f(gl.y),
                         bf2f(gh.z) + bf2f(gl.z), bf2f(gh.w) + bf2f(gl.w)};
    const float uv[4] = {bf2f(uh.x) + bf2f(ul.x), bf2f(uh.y) + bf2f(ul.y),
                         bf2f(uh.z) + bf2f(ul.z), bf2f(uh.w) + bf2f(ul.w)};
    uint16_t rh[4], rl[4];
#pragma unroll
    for (int k = 0; k < 4; k++) {
        const float r = (gv[k] / (1.0f + __expf(-gv[k]))) * uv[k];
        split_bf(r, rh[k], rl[k]);
    }
    uint2 ph, pl;
    ph.x = (uint32_t)rh[0] | ((uint32_t)rh[1] << 16);
    ph.y = (uint32_t)rh[2] | ((uint32_t)rh[3] << 16);
    pl.x = (uint32_t)rl[0] | ((uint32_t)rl[1] << 16);
    pl.y = (uint32_t)rl[2] | ((uint32_t)rl[3] << 16);
    *reinterpret_cast<uint2*>(&ahi[e]) = ph;
    *reinterpret_cast<uint2*>(&alo[e]) = pl;
}

// ---------------------------------------------------------------------------
extern "C" void kernel_launch(void* const* d_in, const int* in_sizes, int n_in,
                              void* d_out, int out_size, void* d_ws, size_t ws_size,
                              hipStream_t stream)
{
    (void)in_sizes; (void)n_in; (void)out_size; (void)ws_size;
    const float* x      = (const float*)d_in[0];
    const int*   wq_q   = (const int*)d_in[1];
    const float* wq_s   = (const float*)d_in[2];
    const float* bq     = (const float*)d_in[3];
    const int*   wk_q   = (const int*)d_in[4];
    const float* wk_s   = (const float*)d_in[5];
    const float* bk     = (const float*)d_in[6];
    const int*   wv_q   = (const int*)d_in[7];
    const float* wv_s   = (const float*)d_in[8];
    const float* bv     = (const float*)d_in[9];
    const int*   wo_q   = (const int*)d_in[10];
    const float* wo_s   = (const float*)d_in[11];
    const int*   gate_q = (const int*)d_in[12];
    const float* gate_s = (const float*)d_in[13];
    const int*   up_q   = (const int*)d_in[14];
    const float* up_s   = (const float*)d_in[15];
    const int*   down_q = (const int*)d_in[16];
    const float* down_s = (const float*)d_in[17];
    const float* w_in   = (const float*)d_in[18];
    const float* w_post = (const float*)d_in[19];
    const int*   offp   = (const int*)d_in[20];

    char* p = (char*)d_ws;
    auto alloc = [&](size_t bytes) {
        char* r = p;
        p += (bytes + 255) & ~(size_t)255;
        return r;
    };
    // persistent region
    uint16_t* Wgu    = (uint16_t*)alloc((size_t)2 * D_FF * D_MODEL * 2);
    uint16_t* Wdown  = (uint16_t*)alloc((size_t)D_MODEL * D_FF * 2);
    float*    sgu    = (float*)alloc((size_t)2 * D_FF * (D_MODEL / 64) * 4);
    float*    x2     = (float*)alloc((size_t)ROWS * D_MODEL * 4);
    uint16_t* gubhi  = (uint16_t*)alloc((size_t)ROWS * 2 * D_FF * 2);
    uint16_t* gublo  = (uint16_t*)alloc((size_t)ROWS * 2 * D_FF * 2);
    uint16_t* hhi    = (uint16_t*)alloc((size_t)ROWS * D_MODEL * 2);  // h, then h2
    uint16_t* hlo    = (uint16_t*)alloc((size_t)ROWS * D_MODEL * 2);
    uint16_t* atthi  = (uint16_t*)alloc((size_t)ROWS * D_MODEL * 2);
    uint16_t* attlo  = (uint16_t*)alloc((size_t)ROWS * D_MODEL * 2);
    // transient zone: Wqkv+Wo+sqkv+bqkv+qkv live until O-proj completes;
    // actb hi/lo (written by silu AFTER O-proj) aliases onto it.
    char* zone = alloc((size_t)N_QKV * D_MODEL * 2 +        // Wqkv 12.58 MB
                       (size_t)D_MODEL * D_MODEL * 2 +      // Wo    8.39 MB
                       (size_t)N_QKV * (D_MODEL / 64) * 4 + // sqkv  0.39 MB
                       (size_t)N_QKV * 4 +                  // bqkv
                       (size_t)ROWS * N_QKV * 4 + 4096);    // qkv  25.17 MB
    uint16_t* Wqkv = (uint16_t*)zone;
    uint16_t* Wo   = Wqkv + (size_t)N_QKV * D_MODEL;
    float*    sqkv = (float*)(Wo + (size_t)D_MODEL * D_MODEL);
    float*    bqkv = sqkv + (size_t)N_QKV * (D_MODEL / 64);
    float*    qkv  = bqkv + N_QKV;
    uint16_t* acthi = (uint16_t*)zone;                       // alias (post O-proj)
    uint16_t* actlo = acthi + (size_t)ROWS * D_FF;

    auto dqe = [&](const int* q, uint16_t* o, size_t n) {
        const int n4 = (int)(n / 4);
        dequant_exact_kernel<<<(n4 + 255) / 256, 256, 0, stream>>>(q, o, n4);
    };
    dqe(wq_q, Wqkv, (size_t)2048 * 2048);
    dqe(wk_q, Wqkv + (size_t)2048 * 2048, (size_t)512 * 2048);
    dqe(wv_q, Wqkv + (size_t)2560 * 2048, (size_t)512 * 2048);
    dqe(wo_q, Wo, (size_t)2048 * 2048);
    dqe(gate_q, Wgu, (size_t)D_FF * 2048);
    dqe(up_q, Wgu + (size_t)D_FF * 2048, (size_t)D_FF * 2048);
    dqe(down_q, Wdown, (size_t)2048 * D_FF);

    // scale concats (device-to-device async copies)
    hipMemcpyAsync(sqkv, wq_s, (size_t)2048 * 32 * 4, hipMemcpyDeviceToDevice, stream);
    hipMemcpyAsync(sqkv + (size_t)2048 * 32, wk_s, (size_t)512 * 32 * 4, hipMemcpyDeviceToDevice, stream);
    hipMemcpyAsync(sqkv + (size_t)2560 * 32, wv_s, (size_t)512 * 32 * 4, hipMemcpyDeviceToDevice, stream);
    hipMemcpyAsync(sgu, gate_s, (size_t)D_FF * 32 * 4, hipMemcpyDeviceToDevice, stream);
    hipMemcpyAsync(sgu + (size_t)D_FF * 32, up_s, (size_t)D_FF * 32 * 4, hipMemcpyDeviceToDevice, stream);

    biascat_kernel<<<(N_QKV + 255) / 256, 256, 0, stream>>>(bq, bk, bv, bqkv);
    rmsnorm_kernel<<<ROWS, 256, 0, stream>>>(x, w_in, hhi, hlo);

    gemm_qbt_kernel<false><<<(ROWS / 128) * (N_QKV / 128), 256, 0, stream>>>(
        hhi, hlo, Wqkv, sqkv, bqkv, nullptr, qkv, nullptr, nullptr,
        ROWS, N_QKV, D_MODEL);

    rope_kernel<<<(ROWS * 20 * 64) / 256, 256, 0, stream>>>(qkv, offp);

    attn_kernel<<<BATCH * HEADS * (SEQ / 16), 256, 0, stream>>>(qkv, atthi, attlo);

    gemm_qbt_kernel<false><<<(ROWS / 128) * (D_MODEL / 128), 256, 0, stream>>>(
        atthi, attlo, Wo, wo_s, nullptr, x, x2, nullptr, nullptr,
        ROWS, D_MODEL, D_MODEL);

    rmsnorm_kernel<<<ROWS, 256, 0, stream>>>(x2, w_post, hhi, hlo);

    gemm_qbt_kernel<true><<<(ROWS / 128) * (2 * D_FF / 128), 256, 0, stream>>>(
        hhi, hlo, Wgu, sgu, nullptr, nullptr, nullptr, gubhi, gublo,
        ROWS, 2 * D_FF, D_MODEL);

    silu_mul_kernel<<<(ROWS * D_FF / 4 + 255) / 256, 256, 0, stream>>>(
        gubhi, gublo, acthi, actlo);

    gemm_qbt_kernel<false><<<(ROWS / 128) * (D_MODEL / 128), 256, 0, stream>>>(
        acthi, actlo, Wdown, down_s, nullptr, x2, (float*)d_out, nullptr, nullptr,
        ROWS, D_MODEL, D_FF);
}

// Round 5
// 1172.185 us; speedup vs baseline: 1.1360x; 1.1360x over previous
//
#include <hip/hip_runtime.h>
#include <cstdint>
#include <cstddef>

#define DEV __device__ __forceinline__

typedef __bf16 bf16x8 __attribute__((ext_vector_type(8)));
typedef float f32x4 __attribute__((ext_vector_type(4)));

static constexpr int D_MODEL = 2048;
static constexpr int D_FF    = 5632;
static constexpr int N_QKV   = 3072;   // 2048 q + 512 k + 512 v
static constexpr int SEQ     = 1024;
static constexpr int BATCH   = 2;
static constexpr int ROWS    = BATCH * SEQ;  // 2048
static constexpr int HEADS   = 16;
static constexpr int HD      = 128;

DEV uint16_t f2bf(float f) {
    uint32_t u = __float_as_uint(f);
    u += 0x7fffu + ((u >> 16) & 1u);   // RTNE
    return (uint16_t)(u >> 16);
}
DEV float bf2f(uint16_t h) { return __uint_as_float(((uint32_t)h) << 16); }
DEV void split_bf(float v, uint16_t& hi, uint16_t& lo) {
    hi = f2bf(v);
    lo = f2bf(v - bf2f(hi));
}

// async global->LDS, 16B/lane; lds ptr must be wave-uniform (HW adds lane*16)
DEV void async_load16(const void* g, void* lds) {
    __builtin_amdgcn_global_load_lds(
        reinterpret_cast<__attribute__((address_space(1))) void*>(
            reinterpret_cast<uintptr_t>(g)),
        reinterpret_cast<__attribute__((address_space(3))) void*>(
            static_cast<uint32_t>(reinterpret_cast<uintptr_t>(lds))),
        16, 0, 0);
}

// ---------------------------------------------------------------------------
// Dequant to hi/lo bf16 pair: w = q*s (fp32), split exact to ~2^-16.
// mode 0: orow=row; mode 1: gate interleave; mode 2: up interleave.
// ---------------------------------------------------------------------------
__global__ __launch_bounds__(256)
void dequant_kernel(const int* __restrict__ q, const float* __restrict__ s,
                    uint16_t* __restrict__ whi, uint16_t* __restrict__ wlo,
                    int n4, int I, int mode)
{
    const int idx = blockIdx.x * 256 + threadIdx.x;
    if (idx >= n4) return;
    const int e = idx * 4;
    const int row = e / I;
    const int i = e - row * I;
    const int4 qv = *reinterpret_cast<const int4*>(&q[e]);
    const float scf = s[row * (I >> 6) + (i >> 6)];
    int orow = row;
    if (mode == 1) orow = ((row >> 4) << 5) + (row & 15);
    else if (mode == 2) orow = ((row >> 4) << 5) + (row & 15) + 16;
    const float w[4] = {(float)qv.x * scf, (float)qv.y * scf,
                        (float)qv.z * scf, (float)qv.w * scf};
    uint16_t h[4], l[4];
#pragma unroll
    for (int k = 0; k < 4; k++) split_bf(w[k], h[k], l[k]);
    uint2 ph, pl;
    ph.x = (uint32_t)h[0] | ((uint32_t)h[1] << 16);
    ph.y = (uint32_t)h[2] | ((uint32_t)h[3] << 16);
    pl.x = (uint32_t)l[0] | ((uint32_t)l[1] << 16);
    pl.y = (uint32_t)l[2] | ((uint32_t)l[3] << 16);
    const size_t ob = (size_t)orow * I + i;
    *reinterpret_cast<uint2*>(&whi[ob]) = ph;
    *reinterpret_cast<uint2*>(&wlo[ob]) = pl;
}

__global__ __launch_bounds__(256)
void biascat_kernel(const float* __restrict__ bq, const float* __restrict__ bk,
                    const float* __restrict__ bv, float* __restrict__ out)
{
    const int i = blockIdx.x * 256 + threadIdx.x;
    if (i >= N_QKV) return;
    float v;
    if (i < 2048)      v = bq[i];
    else if (i < 2560) v = bk[i - 2048];
    else               v = bv[i - 2560];
    out[i] = v;
}

// ---------------------------------------------------------------------------
// RMSNorm (fp32 in) -> hi/lo bf16 pair. One row (2048) per block of 256.
// ---------------------------------------------------------------------------
__global__ __launch_bounds__(256)
void rmsnorm_kernel(const float* __restrict__ x, const float* __restrict__ wln,
                    uint16_t* __restrict__ ohi, uint16_t* __restrict__ olo)
{
    __shared__ float red[4];
    const int row = blockIdx.x;
    const int tid = threadIdx.x;
    const float* xr = x + (size_t)row * D_MODEL;
    const float4 v0 = *reinterpret_cast<const float4*>(&xr[tid * 8]);
    const float4 v1 = *reinterpret_cast<const float4*>(&xr[tid * 8 + 4]);
    float ss = v0.x*v0.x + v0.y*v0.y + v0.z*v0.z + v0.w*v0.w
             + v1.x*v1.x + v1.y*v1.y + v1.z*v1.z + v1.w*v1.w;
#pragma unroll
    for (int off = 32; off; off >>= 1) ss += __shfl_xor(ss, off);
    if ((tid & 63) == 0) red[tid >> 6] = ss;
    __syncthreads();
    const float rms = rsqrtf((red[0] + red[1] + red[2] + red[3]) * (1.0f / D_MODEL) + 1e-6f);
    const int cb = tid * 8;
    const size_t base = (size_t)row * D_MODEL + cb;
    const float vals[8] = {v0.x, v0.y, v0.z, v0.w, v1.x, v1.y, v1.z, v1.w};
#pragma unroll
    for (int k = 0; k < 8; k += 2) {
        uint16_t h0, l0, h1, l1;
        split_bf(vals[k] * rms * wln[cb + k], h0, l0);
        split_bf(vals[k + 1] * rms * wln[cb + k + 1], h1, l1);
        *reinterpret_cast<uint32_t*>(&ohi[base + k]) = (uint32_t)h0 | ((uint32_t)h1 << 16);
        *reinterpret_cast<uint32_t*>(&olo[base + k]) = (uint32_t)l0 | ((uint32_t)l1 << 16);
    }
}

// ---------------------------------------------------------------------------
// 3-term hi/lo GEMM: C = (Ah+Al)·(Wh+Wl)^T ≈ AhWh + AhWl + AlWh (fp32 acc).
// A (M,K), W (N,K) bf16 row-major. 128x128 tile, BK=32, 4 waves 2x2,
// wave 4x4 MFMA 16x16x32. EPI 0: fp32 out (+bias/+resid).
// EPI 2: fused SwiGLU (W interleaved gate/up by 16-col blocks), split out.
// ---------------------------------------------------------------------------
template <int EPI>
__global__ __launch_bounds__(256)
void gemm3_kernel(const uint16_t* __restrict__ Ah, const uint16_t* __restrict__ Al,
                  const uint16_t* __restrict__ Wh, const uint16_t* __restrict__ Wl,
                  const float* __restrict__ bias, const float* __restrict__ resid,
                  float* __restrict__ outf, uint16_t* __restrict__ ohi,
                  uint16_t* __restrict__ olo, int M, int N, int K)
{
    __shared__ uint16_t sAh[128 * 32];
    __shared__ uint16_t sAl[128 * 32];
    __shared__ uint16_t sBh[128 * 32];
    __shared__ uint16_t sBl[128 * 32];

    const int tid  = threadIdx.x;
    const int lane = tid & 63;
    const int wv   = tid >> 6;
    const int wm   = wv >> 1;
    const int wn   = wv & 1;
    const int quad = lane >> 4;
    const int l16  = lane & 15;

    const int nBn = N >> 7;
    const int bm  = blockIdx.x / nBn;
    const int bn  = blockIdx.x - bm * nBn;
    const int m0  = bm << 7;
    const int n0  = bn << 7;

    f32x4 acc[4][4];
#pragma unroll
    for (int i = 0; i < 4; i++)
#pragma unroll
        for (int j = 0; j < 4; j++)
            acc[i][j] = (f32x4){0.f, 0.f, 0.f, 0.f};

    const uint16_t* Abh = Ah + (size_t)m0 * K;
    const uint16_t* Abl = Al + (size_t)m0 * K;
    const uint16_t* Wbh = Wh + (size_t)n0 * K;
    const uint16_t* Wbl = Wl + (size_t)n0 * K;

    for (int kt = 0; kt < K; kt += 32) {
        __syncthreads();
#pragma unroll
        for (int p = 0; p < 2; p++) {
            const int cb = p * 256 + wv * 64;          // wave-uniform chunk base
            const int c  = cb + lane;
            const int row = c >> 2, e = (c & 3) * 8;
            const size_t goff = (size_t)row * K + kt + e;
            async_load16(Abh + goff, &sAh[cb * 8]);
            async_load16(Abl + goff, &sAl[cb * 8]);
            async_load16(Wbh + goff, &sBh[cb * 8]);
            async_load16(Wbl + goff, &sBl[cb * 8]);
        }
        __syncthreads();

        bf16x8 bh[4], bl[4];
#pragma unroll
        for (int j = 0; j < 4; j++) {
            const int off = (wn * 64 + j * 16 + l16) * 32 + quad * 8;
            bh[j] = *reinterpret_cast<const bf16x8*>(&sBh[off]);
            bl[j] = *reinterpret_cast<const bf16x8*>(&sBl[off]);
        }
#pragma unroll
        for (int i = 0; i < 4; i++) {
            const int ra = (wm * 64 + i * 16 + l16) * 32 + quad * 8;
            const bf16x8 ah = *reinterpret_cast<const bf16x8*>(&sAh[ra]);
            const bf16x8 al = *reinterpret_cast<const bf16x8*>(&sAl[ra]);
#pragma unroll
            for (int j = 0; j < 4; j++)
                acc[i][j] = __builtin_amdgcn_mfma_f32_16x16x32_bf16(ah, bh[j], acc[i][j], 0, 0, 0);
#pragma unroll
            for (int j = 0; j < 4; j++)
                acc[i][j] = __builtin_amdgcn_mfma_f32_16x16x32_bf16(ah, bl[j], acc[i][j], 0, 0, 0);
#pragma unroll
            for (int j = 0; j < 4; j++)
                acc[i][j] = __builtin_amdgcn_mfma_f32_16x16x32_bf16(al, bh[j], acc[i][j], 0, 0, 0);
        }
    }

    // epilogue: C row = quad*4+reg, col = lane&15 (m89-verified)
    if constexpr (EPI == 0) {
#pragma unroll
        for (int i = 0; i < 4; i++) {
            const int rowb = m0 + wm * 64 + i * 16 + quad * 4;
#pragma unroll
            for (int r = 0; r < 4; r++) {
                const size_t rr = (size_t)(rowb + r);
#pragma unroll
                for (int j = 0; j < 4; j++) {
                    const int cc = n0 + wn * 64 + j * 16 + l16;
                    float v = acc[i][j][r];
                    if (bias)  v += bias[cc];
                    if (resid) v += resid[rr * N + cc];
                    outf[rr * N + cc] = v;
                }
            }
        }
    } else {
        // SwiGLU fusion: j even = gate block, j odd = up block of the same
        // original 16-col group. Pair index = bn*4 + wn*2 + pjt
        //   -> output col base = 16*pair = (n0>>1) + wn*32 + pjt*16.
        const int NH = N >> 1;
#pragma unroll
        for (int i = 0; i < 4; i++) {
            const int rowb = m0 + wm * 64 + i * 16 + quad * 4;
#pragma unroll
            for (int r = 0; r < 4; r++) {
                const size_t rr = (size_t)(rowb + r);
#pragma unroll
                for (int pjt = 0; pjt < 2; pjt++) {
                    const float g = acc[i][2 * pjt][r];
                    const float u = acc[i][2 * pjt + 1][r];
                    const float a = (g / (1.0f + __expf(-g))) * u;
                    uint16_t h, l;
                    split_bf(a, h, l);
                    const int cc = (n0 >> 1) + wn * 32 + pjt * 16 + l16;
                    ohi[rr * NH + cc] = h;
                    olo[rr * NH + cc] = l;
                }
            }
        }
    }
}

// ---------------------------------------------------------------------------
// RoPE prep Q: qkv fp32 -> Qb hi/lo bf16 [(b*16+h)*1024+s][128], scaled.
// ---------------------------------------------------------------------------
__global__ __launch_bounds__(256)
void rope_q_kernel(const float* __restrict__ qkv, const int* __restrict__ offp,
                   uint16_t* __restrict__ Qh, uint16_t* __restrict__ Ql)
{
    const int idx = blockIdx.x * 256 + threadIdx.x;   // ROWS*16*64
    const int d   = idx & 63;
    const int h   = (idx >> 6) & 15;
    const int row = idx >> 10;
    const int b   = row >> 10;
    const int s   = row & (SEQ - 1);
    const float pos  = (float)(s + *offp);
    const float freq = powf(1.0e6f, -(float)d * (1.0f / 64.0f));
    float sn, cs;
    sincosf(pos * freq, &sn, &cs);
    const size_t gb = (size_t)row * N_QKV + h * HD + d;
    const float x1 = qkv[gb];
    const float x2 = qkv[gb + 64];
    const float qscale = 0.08838834764831845f;   // 1/sqrt(128)
    const float o1 = (x1 * cs - x2 * sn) * qscale;
    const float o2 = (x2 * cs + x1 * sn) * qscale;
    const size_t ob = ((size_t)(b * 16 + h) * SEQ + s) * HD + d;
    uint16_t h1, l1, h2, l2;
    split_bf(o1, h1, l1);
    split_bf(o2, h2, l2);
    Qh[ob] = h1;  Ql[ob] = l1;
    Qh[ob + 64] = h2;  Ql[ob + 64] = l2;
}

// RoPE prep K: qkv fp32 -> Kb hi/lo bf16 [(b*4+kvh)*1024+s][128], unscaled.
__global__ __launch_bounds__(256)
void rope_k_kernel(const float* __restrict__ qkv, const int* __restrict__ offp,
                   uint16_t* __restrict__ Kh, uint16_t* __restrict__ Kl)
{
    const int idx = blockIdx.x * 256 + threadIdx.x;   // ROWS*4*64
    const int d   = idx & 63;
    const int kvh = (idx >> 6) & 3;
    const int row = idx >> 8;
    const int b   = row >> 10;
    const int s   = row & (SEQ - 1);
    const float pos  = (float)(s + *offp);
    const float freq = powf(1.0e6f, -(float)d * (1.0f / 64.0f));
    float sn, cs;
    sincosf(pos * freq, &sn, &cs);
    const size_t gb = (size_t)row * N_QKV + 2048 + kvh * HD + d;
    const float x1 = qkv[gb];
    const float x2 = qkv[gb + 64];
    const float o1 = x1 * cs - x2 * sn;
    const float o2 = x2 * cs + x1 * sn;
    const size_t ob = ((size_t)(b * 4 + kvh) * SEQ + s) * HD + d;
    uint16_t h1, l1, h2, l2;
    split_bf(o1, h1, l1);
    split_bf(o2, h2, l2);
    Kh[ob] = h1;  Kl[ob] = l1;
    Kh[ob + 64] = h2;  Kl[ob + 64] = l2;
}

// V transpose prep: qkv fp32 -> Vt hi/lo bf16 [(b*4+kvh)*128+dim][1024 keys].
// Block = 64 keys x 128 dims = 2048 float4s -> 8 iters of 256 threads.
__global__ __launch_bounds__(256)
void prep_v_kernel(const float* __restrict__ qkv,
                   uint16_t* __restrict__ Vh, uint16_t* __restrict__ Vl)
{
    __shared__ uint16_t sh[128 * 72];
    __shared__ uint16_t sl[128 * 72];
    const int tid = threadIdx.x;
    const int sc  = blockIdx.x & 15;     // 16 chunks of 64 keys
    const int bk  = blockIdx.x >> 4;     // b*4+kvh
    const int b   = bk >> 2, kvh = bk & 3;
#pragma unroll
    for (int p = 0; p < 8; p++) {
        const int q4 = p * 256 + tid;    // 2048 float4s: 64 rows x 32
        const int sloc = q4 >> 5, d4 = (q4 & 31) * 4;
        const float4 v = *reinterpret_cast<const float4*>(
            &qkv[(size_t)(b * SEQ + sc * 64 + sloc) * N_QKV + 2560 + kvh * HD + d4]);
        const float vv[4] = {v.x, v.y, v.z, v.w};
#pragma unroll
        for (int k = 0; k < 4; k++) {
            uint16_t hh, ll;
            split_bf(vv[k], hh, ll);
            sh[(d4 + k) * 72 + sloc] = hh;
            sl[(d4 + k) * 72 + sloc] = ll;
        }
    }
    __syncthreads();
    const int d = tid >> 1, half = tid & 1;
    const size_t ob = ((size_t)(bk * 128 + d)) * SEQ + sc * 64 + half * 32;
    const uint16_t* srh = &sh[d * 72 + half * 32];
    const uint16_t* srl = &sl[d * 72 + half * 32];
#pragma unroll
    for (int k = 0; k < 4; k++) {
        *reinterpret_cast<uint4*>(&Vh[ob + k * 8]) =
            *reinterpret_cast<const uint4*>(&srh[k * 8]);
        *reinterpret_cast<uint4*>(&Vl[ob + k * 8]) =
            *reinterpret_cast<const uint4*>(&srl[k * 8]);
    }
}

// ---------------------------------------------------------------------------
// MFMA flash attention. Block = 64 Q rows of one (b,h); 4 waves x 16 rows.
// 32-key tiles: K hi/lo [32][128] (XOR-swizzled granules), V^T hi/lo [128][32],
// P hi/lo [wave][16][32] contiguous (wave-private). Online softmax per-lane
// (C-layout rows). Output hi/lo bf16 [row][h*128+d].
// ---------------------------------------------------------------------------
__global__ __launch_bounds__(256)
void attn_kernel(const uint16_t* __restrict__ Qh, const uint16_t* __restrict__ Ql,
                 const uint16_t* __restrict__ Kh, const uint16_t* __restrict__ Kl,
                 const uint16_t* __restrict__ Vh, const uint16_t* __restrict__ Vl,
                 uint16_t* __restrict__ atth, uint16_t* __restrict__ attl)
{
    __shared__ uint16_t sKh[32 * 128];
    __shared__ uint16_t sKl[32 * 128];
    __shared__ uint16_t sVh[128 * 32];
    __shared__ uint16_t sVl[128 * 32];
    __shared__ uint16_t sPh[4 * 16 * 32];
    __shared__ uint16_t sPl[4 * 16 * 32];

    const int tid  = threadIdx.x;
    const int lane = tid & 63;
    const int wv   = tid >> 6;
    const int quad = lane >> 4;
    const int l16  = lane & 15;

    const int bi  = blockIdx.x;
    const int sc  = 15 - (bi >> 5);      // big Q-tiles dispatched first
    const int bh  = bi & 31;
    const int b   = bh >> 4;
    const int h   = bh & 15;
    const int kvh = h >> 2;
    const int s0  = sc << 6;

    // Q fragments (A-layout) straight from global, once.
    bf16x8 qh[4], ql[4];
    {
        const size_t qb = ((size_t)(b * 16 + h) * SEQ + s0 + wv * 16 + l16) * HD;
#pragma unroll
        for (int ks = 0; ks < 4; ks++) {
            const size_t off = qb + ks * 32 + quad * 8;
            qh[ks] = *reinterpret_cast<const bf16x8*>(&Qh[off]);
            ql[ks] = *reinterpret_cast<const bf16x8*>(&Ql[off]);
        }
    }

    float m_i[4], l_i[4];
#pragma unroll
    for (int r = 0; r < 4; r++) { m_i[r] = -1e30f; l_i[r] = 0.f; }
    f32x4 oacc[8];
#pragma unroll
    for (int dt = 0; dt < 8; dt++) oacc[dt] = (f32x4){0.f, 0.f, 0.f, 0.f};

    const size_t kb = (size_t)(b * 4 + kvh) * SEQ * HD;        // K base (elems)
    const size_t vb = (size_t)(b * 4 + kvh) * HD * SEQ;        // V^T base

    const int ntiles = 2 * sc + 2;
    for (int tt = 0; tt < ntiles; tt++) {
        const int t0 = tt << 5;
        __syncthreads();
        // stage K (swizzled source) and V^T
#pragma unroll
        for (int p = 0; p < 2; p++) {
            const int cb = p * 256 + wv * 64;
            const int c  = cb + lane;
            const int krow = c >> 4;
            const int kcc  = (c & 15) ^ (krow & 7);
            const size_t kg = kb + (size_t)(t0 + krow) * HD + kcc * 8;
            async_load16(Kh + kg, &sKh[cb * 8]);
            async_load16(Kl + kg, &sKl[cb * 8]);
            const int vrow = c >> 2;
            const int vcc  = c & 3;
            const size_t vg = vb + (size_t)vrow * SEQ + t0 + vcc * 8;
            async_load16(Vh + vg, &sVh[cb * 8]);
            async_load16(Vl + vg, &sVl[cb * 8]);
        }
        __syncthreads();

        // S = Q·K^T  (3-term hi/lo)
        f32x4 sacc[2];
        sacc[0] = (f32x4){0.f, 0.f, 0.f, 0.f};
        sacc[1] = (f32x4){0.f, 0.f, 0.f, 0.f};
#pragma unroll
        for (int ks = 0; ks < 4; ks++) {
            bf16x8 khf[2], klf[2];
#pragma unroll
            for (int jt = 0; jt < 2; jt++) {
                const int idx = (jt * 16 + l16) * 128 + (((ks * 4 + quad) ^ (l16 & 7)) * 8);
                khf[jt] = *reinterpret_cast<const bf16x8*>(&sKh[idx]);
                klf[jt] = *reinterpret_cast<const bf16x8*>(&sKl[idx]);
            }
#pragma unroll
            for (int jt = 0; jt < 2; jt++)
                sacc[jt] = __builtin_amdgcn_mfma_f32_16x16x32_bf16(qh[ks], khf[jt], sacc[jt], 0, 0, 0);
#pragma unroll
            for (int jt = 0; jt < 2; jt++)
                sacc[jt] = __builtin_amdgcn_mfma_f32_16x16x32_bf16(qh[ks], klf[jt], sacc[jt], 0, 0, 0);
#pragma unroll
            for (int jt = 0; jt < 2; jt++)
                sacc[jt] = __builtin_amdgcn_mfma_f32_16x16x32_bf16(ql[ks], khf[jt], sacc[jt], 0, 0, 0);
        }

        // causal mask (only diagonal-region tiles)
        if (t0 >= s0) {
            const int rowg = s0 + wv * 16 + quad * 4;
#pragma unroll
            for (int jt = 0; jt < 2; jt++) {
                const int key = t0 + jt * 16 + l16;
#pragma unroll
                for (int r = 0; r < 4; r++)
                    if (key > rowg + r) sacc[jt][r] = -1e30f;
            }
        }

        // online softmax per reg (rows quad*4+reg; reduce over 16 l16 lanes)
        float alpha[4];
#pragma unroll
        for (int r = 0; r < 4; r++) {
            float mt = fmaxf(sacc[0][r], sacc[1][r]);
#pragma unroll
            for (int off = 8; off; off >>= 1) mt = fmaxf(mt, __shfl_xor(mt, off));
            const float mn = fmaxf(m_i[r], mt);
            alpha[r] = __expf(m_i[r] - mn);
            const float p0 = __expf(sacc[0][r] - mn);
            const float p1 = __expf(sacc[1][r] - mn);
            float ps = p0 + p1;
#pragma unroll
            for (int off = 8; off; off >>= 1) ps += __shfl_xor(ps, off);
            l_i[r] = l_i[r] * alpha[r] + ps;
            m_i[r] = mn;
            // write P hi/lo: wave-private block, row = quad*4+r, key = jt*16+l16
            const int prow = quad * 4 + r;
            uint16_t ph, pl;
#pragma unroll
            for (int jt = 0; jt < 2; jt++) {
                const float pv = jt ? p1 : p0;
                const int key = jt * 16 + l16;
                const int idx = wv * 512 + prow * 32 + key;
                split_bf(pv, ph, pl);
                sPh[idx] = ph;
                sPl[idx] = pl;
            }
        }
        __syncthreads();

        // rescale O by alpha, then PV (3-term hi/lo)
#pragma unroll
        for (int dt = 0; dt < 8; dt++) {
#pragma unroll
            for (int r = 0; r < 4; r++) oacc[dt][r] *= alpha[r];
        }
        const int pidx = wv * 512 + l16 * 32 + quad * 8;
        const bf16x8 pfh = *reinterpret_cast<const bf16x8*>(&sPh[pidx]);
        const bf16x8 pfl = *reinterpret_cast<const bf16x8*>(&sPl[pidx]);
#pragma unroll
        for (int dt = 0; dt < 8; dt++) {
            const int vidx = (dt * 16 + l16) * 32 + quad * 8;
            const bf16x8 vhf = *reinterpret_cast<const bf16x8*>(&sVh[vidx]);
            const bf16x8 vlf = *reinterpret_cast<const bf16x8*>(&sVl[vidx]);
            oacc[dt] = __builtin_amdgcn_mfma_f32_16x16x32_bf16(pfh, vhf, oacc[dt], 0, 0, 0);
            oacc[dt] = __builtin_amdgcn_mfma_f32_16x16x32_bf16(pfh, vlf, oacc[dt], 0, 0, 0);
            oacc[dt] = __builtin_amdgcn_mfma_f32_16x16x32_bf16(pfl, vhf, oacc[dt], 0, 0, 0);
        }
    }

    // final normalize + store (C-layout rows)
    float inv[4];
#pragma unroll
    for (int r = 0; r < 4; r++) inv[r] = 1.0f / l_i[r];
#pragma unroll
    for (int r = 0; r < 4; r++) {
        const size_t rowg = (size_t)(b * SEQ + s0 + wv * 16 + quad * 4 + r);
#pragma unroll
        for (int dt = 0; dt < 8; dt++) {
            const float v = oacc[dt][r] * inv[r];
            uint16_t hh, ll;
            split_bf(v, hh, ll);
            const size_t off = rowg * D_MODEL + h * HD + dt * 16 + l16;
            atth[off] = hh;
            attl[off] = ll;
        }
    }
}

// ---------------------------------------------------------------------------
extern "C" void kernel_launch(void* const* d_in, const int* in_sizes, int n_in,
                              void* d_out, int out_size, void* d_ws, size_t ws_size,
                              hipStream_t stream)
{
    (void)in_sizes; (void)n_in; (void)out_size; (void)ws_size;
    const float* x      = (const float*)d_in[0];
    const int*   wq_q   = (const int*)d_in[1];
    const float* wq_s   = (const float*)d_in[2];
    const float* bq     = (const float*)d_in[3];
    const int*   wk_q   = (const int*)d_in[4];
    const float* wk_s   = (const float*)d_in[5];
    const float* bk     = (const float*)d_in[6];
    const int*   wv_q   = (const int*)d_in[7];
    const float* wv_s   = (const float*)d_in[8];
    const float* bv     = (const float*)d_in[9];
    const int*   wo_q   = (const int*)d_in[10];
    const float* wo_s   = (const float*)d_in[11];
    const int*   gate_q = (const int*)d_in[12];
    const float* gate_s = (const float*)d_in[13];
    const int*   up_q   = (const int*)d_in[14];
    const float* up_s   = (const float*)d_in[15];
    const int*   down_q = (const int*)d_in[16];
    const float* down_s = (const float*)d_in[17];
    const float* w_in   = (const float*)d_in[18];
    const float* w_post = (const float*)d_in[19];
    const int*   offp   = (const int*)d_in[20];

    char* p = (char*)d_ws;
    auto alloc = [&](size_t bytes) {
        char* r = p;
        p += (bytes + 255) & ~(size_t)255;
        return r;
    };
    // persistent
    uint16_t* Wguh   = (uint16_t*)alloc((size_t)2 * D_FF * D_MODEL * 2);  // 46.1 MB
    uint16_t* Wgul   = (uint16_t*)alloc((size_t)2 * D_FF * D_MODEL * 2);
    uint16_t* Wdownh = (uint16_t*)alloc((size_t)D_MODEL * D_FF * 2);      // 23.1 MB
    uint16_t* Wdownl = (uint16_t*)alloc((size_t)D_MODEL * D_FF * 2);
    uint16_t* hh     = (uint16_t*)alloc((size_t)ROWS * D_MODEL * 2);      // h / h2
    uint16_t* hl     = (uint16_t*)alloc((size_t)ROWS * D_MODEL * 2);
    float*    x2     = (float*)alloc((size_t)ROWS * D_MODEL * 4);
    float*    bqkv   = (float*)alloc((size_t)N_QKV * 4);
    // transient zone: Wqkv h/l | Wo h/l | qkv  (aliased later)
    char* zone = alloc((size_t)N_QKV * D_MODEL * 2 * 2 +
                       (size_t)D_MODEL * D_MODEL * 2 * 2 +
                       (size_t)ROWS * N_QKV * 4 + 8192);
    uint16_t* Wqkvh = (uint16_t*)zone;
    uint16_t* Wqkvl = Wqkvh + (size_t)N_QKV * D_MODEL;
    uint16_t* Woh   = Wqkvl + (size_t)N_QKV * D_MODEL;
    uint16_t* Wol   = Woh + (size_t)D_MODEL * D_MODEL;
    float*    qkv   = (float*)(Wol + (size_t)D_MODEL * D_MODEL);
    // prep buffers alias Wqkv h/l (dead after QKV GEMM): exactly 25.17 MB
    uint16_t* Qbh = Wqkvh;                               // 8.39 MB
    uint16_t* Qbl = Qbh + (size_t)BATCH * 16 * SEQ * HD;
    uint16_t* Kbh = Qbl + (size_t)BATCH * 16 * SEQ * HD; // 2.10 MB
    uint16_t* Kbl = Kbh + (size_t)BATCH * 4 * SEQ * HD;
    uint16_t* Vth = Kbl + (size_t)BATCH * 4 * SEQ * HD;
    uint16_t* Vtl = Vth + (size_t)BATCH * 4 * SEQ * HD;
    // attention output aliases qkv (dead after preps)
    uint16_t* atth = (uint16_t*)qkv;
    uint16_t* attl = atth + (size_t)ROWS * D_MODEL;
    // act hi/lo aliases zone start (everything there dead after O-proj)
    uint16_t* acth = (uint16_t*)zone;
    uint16_t* actl = acth + (size_t)ROWS * D_FF;

    auto dq = [&](const int* q, const float* s, uint16_t* oh, uint16_t* ol,
                  size_t n, int I, int mode) {
        const int n4 = (int)(n / 4);
        dequant_kernel<<<(n4 + 255) / 256, 256, 0, stream>>>(q, s, oh, ol, n4, I, mode);
    };
    dq(wq_q, wq_s, Wqkvh, Wqkvl, (size_t)2048 * 2048, 2048, 0);
    dq(wk_q, wk_s, Wqkvh + (size_t)2048 * 2048, Wqkvl + (size_t)2048 * 2048,
       (size_t)512 * 2048, 2048, 0);
    dq(wv_q, wv_s, Wqkvh + (size_t)2560 * 2048, Wqkvl + (size_t)2560 * 2048,
       (size_t)512 * 2048, 2048, 0);
    dq(wo_q, wo_s, Woh, Wol, (size_t)2048 * 2048, 2048, 0);
    dq(gate_q, gate_s, Wguh, Wgul, (size_t)D_FF * 2048, 2048, 1);
    dq(up_q, up_s, Wguh, Wgul, (size_t)D_FF * 2048, 2048, 2);
    dq(down_q, down_s, Wdownh, Wdownl, (size_t)2048 * D_FF, D_FF, 0);

    biascat_kernel<<<(N_QKV + 255) / 256, 256, 0, stream>>>(bq, bk, bv, bqkv);
    rmsnorm_kernel<<<ROWS, 256, 0, stream>>>(x, w_in, hh, hl);

    gemm3_kernel<0><<<(ROWS / 128) * (N_QKV / 128), 256, 0, stream>>>(
        hh, hl, Wqkvh, Wqkvl, bqkv, nullptr, qkv, nullptr, nullptr,
        ROWS, N_QKV, D_MODEL);

    rope_q_kernel<<<(ROWS * 16 * 64) / 256, 256, 0, stream>>>(qkv, offp, Qbh, Qbl);
    rope_k_kernel<<<(ROWS * 4 * 64) / 256, 256, 0, stream>>>(qkv, offp, Kbh, Kbl);
    prep_v_kernel<<<BATCH * 4 * (SEQ / 64), 256, 0, stream>>>(qkv, Vth, Vtl);

    attn_kernel<<<BATCH * HEADS * (SEQ / 64), 256, 0, stream>>>(
        Qbh, Qbl, Kbh, Kbl, Vth, Vtl, atth, attl);

    gemm3_kernel<0><<<(ROWS / 128) * (D_MODEL / 128), 256, 0, stream>>>(
        atth, attl, Woh, Wol, nullptr, x, x2, nullptr, nullptr,
        ROWS, D_MODEL, D_MODEL);

    rmsnorm_kernel<<<ROWS, 256, 0, stream>>>(x2, w_post, hh, hl);

    gemm3_kernel<2><<<(ROWS / 128) * (2 * D_FF / 128), 256, 0, stream>>>(
        hh, hl, Wguh, Wgul, nullptr, nullptr, nullptr, acth, actl,
        ROWS, 2 * D_FF, D_MODEL);

    gemm3_kernel<0><<<(ROWS / 128) * (D_MODEL / 128), 256, 0, stream>>>(
        acth, actl, Wdownh, Wdownl, nullptr, x2, (float*)d_out, nullptr, nullptr,
        ROWS, D_MODEL, D_FF);
}

// Round 6
// 723.861 us; speedup vs baseline: 1.8396x; 1.6194x over previous
//
#include <hip/hip_runtime.h>
#include <cstdint>
#include <cstddef>

#define DEV __device__ __forceinline__

typedef _Float16 f16x8 __attribute__((ext_vector_type(8)));
typedef float f32x4 __attribute__((ext_vector_type(4)));

static constexpr int D_MODEL = 2048;
static constexpr int D_FF    = 5632;
static constexpr int N_QKV   = 3072;   // 2048 q + 512 k + 512 v
static constexpr int SEQ     = 1024;
static constexpr int BATCH   = 2;
static constexpr int ROWS    = BATCH * SEQ;  // 2048
static constexpr int HEADS   = 16;
static constexpr int HD      = 128;

DEV uint16_t f2h(float f) {
    return __builtin_bit_cast(uint16_t, (_Float16)f);   // RTNE, 2^-12 RMS rel err
}
DEV float h2f(uint16_t u) {
    return (float)__builtin_bit_cast(_Float16, u);
}

// async global->LDS, 16B/lane; lds ptr must be wave-uniform (HW adds lane*16)
DEV void async_load16(const void* g, void* lds) {
    __builtin_amdgcn_global_load_lds(
        reinterpret_cast<__attribute__((address_space(1))) void*>(
            reinterpret_cast<uintptr_t>(g)),
        reinterpret_cast<__attribute__((address_space(3))) void*>(
            static_cast<uint32_t>(reinterpret_cast<uintptr_t>(lds))),
        16, 0, 0);
}

// ---------------------------------------------------------------------------
// Dequant to fp16: w = q*s (fp32) -> _Float16 (rel err 2^-12).
// mode 0: orow=row; mode 1: gate interleave; mode 2: up interleave.
// ---------------------------------------------------------------------------
__global__ __launch_bounds__(256)
void dequant_kernel(const int* __restrict__ q, const float* __restrict__ s,
                    uint16_t* __restrict__ wout, int n4, int I, int mode)
{
    const int idx = blockIdx.x * 256 + threadIdx.x;
    if (idx >= n4) return;
    const int e = idx * 4;
    const int row = e / I;
    const int i = e - row * I;
    const int4 qv = *reinterpret_cast<const int4*>(&q[e]);
    const float scf = s[row * (I >> 6) + (i >> 6)];
    int orow = row;
    if (mode == 1) orow = ((row >> 4) << 5) + (row & 15);
    else if (mode == 2) orow = ((row >> 4) << 5) + (row & 15) + 16;
    uint16_t h[4];
    h[0] = f2h((float)qv.x * scf);
    h[1] = f2h((float)qv.y * scf);
    h[2] = f2h((float)qv.z * scf);
    h[3] = f2h((float)qv.w * scf);
    uint2 pk;
    pk.x = (uint32_t)h[0] | ((uint32_t)h[1] << 16);
    pk.y = (uint32_t)h[2] | ((uint32_t)h[3] << 16);
    *reinterpret_cast<uint2*>(&wout[(size_t)orow * I + i]) = pk;
}

__global__ __launch_bounds__(256)
void biascat_kernel(const float* __restrict__ bq, const float* __restrict__ bk,
                    const float* __restrict__ bv, float* __restrict__ out)
{
    const int i = blockIdx.x * 256 + threadIdx.x;
    if (i >= N_QKV) return;
    float v;
    if (i < 2048)      v = bq[i];
    else if (i < 2560) v = bk[i - 2048];
    else               v = bv[i - 2560];
    out[i] = v;
}

// ---------------------------------------------------------------------------
// RMSNorm (fp32 in) -> fp16. One row (2048) per block of 256.
// ---------------------------------------------------------------------------
__global__ __launch_bounds__(256)
void rmsnorm_kernel(const float* __restrict__ x, const float* __restrict__ wln,
                    uint16_t* __restrict__ out)
{
    __shared__ float red[4];
    const int row = blockIdx.x;
    const int tid = threadIdx.x;
    const float* xr = x + (size_t)row * D_MODEL;
    const float4 v0 = *reinterpret_cast<const float4*>(&xr[tid * 8]);
    const float4 v1 = *reinterpret_cast<const float4*>(&xr[tid * 8 + 4]);
    float ss = v0.x*v0.x + v0.y*v0.y + v0.z*v0.z + v0.w*v0.w
             + v1.x*v1.x + v1.y*v1.y + v1.z*v1.z + v1.w*v1.w;
#pragma unroll
    for (int off = 32; off; off >>= 1) ss += __shfl_xor(ss, off);
    if ((tid & 63) == 0) red[tid >> 6] = ss;
    __syncthreads();
    const float rms = rsqrtf((red[0] + red[1] + red[2] + red[3]) * (1.0f / D_MODEL) + 1e-6f);
    const int cb = tid * 8;
    const size_t base = (size_t)row * D_MODEL + cb;
    const float vals[8] = {v0.x, v0.y, v0.z, v0.w, v1.x, v1.y, v1.z, v1.w};
#pragma unroll
    for (int k = 0; k < 8; k += 2) {
        const uint16_t h0 = f2h(vals[k] * rms * wln[cb + k]);
        const uint16_t h1 = f2h(vals[k + 1] * rms * wln[cb + k + 1]);
        *reinterpret_cast<uint32_t*>(&out[base + k]) = (uint32_t)h0 | ((uint32_t)h1 << 16);
    }
}

// ---------------------------------------------------------------------------
// fp16 GEMM: C[m,n] = A[m,:]·W[n,:] (fp32 acc). A (M,K), W (N,K) row-major.
// 128x128 tile, BK=32, 4 waves 2x2, wave 4x4 MFMA 16x16x32 f16 (m97 shape).
// EPI 0: fp32 out (+bias/+resid).
// EPI 2: fused SwiGLU (W interleaved gate/up by 16-col blocks), fp16 out.
// ---------------------------------------------------------------------------
template <int EPI>
__global__ __launch_bounds__(256)
void gemm_f16_kernel(const uint16_t* __restrict__ A, const uint16_t* __restrict__ W,
                     const float* __restrict__ bias, const float* __restrict__ resid,
                     float* __restrict__ outf, uint16_t* __restrict__ outh,
                     int M, int N, int K)
{
    __shared__ uint16_t sA[128 * 32];
    __shared__ uint16_t sB[128 * 32];

    const int tid  = threadIdx.x;
    const int lane = tid & 63;
    const int wv   = tid >> 6;
    const int wm   = wv >> 1;
    const int wn   = wv & 1;
    const int quad = lane >> 4;
    const int l16  = lane & 15;

    const int nBn = N >> 7;
    const int bm  = blockIdx.x / nBn;
    const int bn  = blockIdx.x - bm * nBn;
    const int m0  = bm << 7;
    const int n0  = bn << 7;

    f32x4 acc[4][4];
#pragma unroll
    for (int i = 0; i < 4; i++)
#pragma unroll
        for (int j = 0; j < 4; j++)
            acc[i][j] = (f32x4){0.f, 0.f, 0.f, 0.f};

    const uint16_t* Ab = A + (size_t)m0 * K;
    const uint16_t* Wb = W + (size_t)n0 * K;

    for (int kt = 0; kt < K; kt += 32) {
        __syncthreads();
#pragma unroll
        for (int p = 0; p < 2; p++) {
            const int cb = p * 256 + wv * 64;          // wave-uniform chunk base
            const int c  = cb + lane;
            const int row = c >> 2, e = (c & 3) * 8;
            const size_t goff = (size_t)row * K + kt + e;
            async_load16(Ab + goff, &sA[cb * 8]);
            async_load16(Wb + goff, &sB[cb * 8]);
        }
        __syncthreads();

        f16x8 bf[4];
#pragma unroll
        for (int j = 0; j < 4; j++)
            bf[j] = *reinterpret_cast<const f16x8*>(
                &sB[(wn * 64 + j * 16 + l16) * 32 + quad * 8]);
#pragma unroll
        for (int i = 0; i < 4; i++) {
            const f16x8 af = *reinterpret_cast<const f16x8*>(
                &sA[(wm * 64 + i * 16 + l16) * 32 + quad * 8]);
#pragma unroll
            for (int j = 0; j < 4; j++)
                acc[i][j] = __builtin_amdgcn_mfma_f32_16x16x32_f16(af, bf[j], acc[i][j], 0, 0, 0);
        }
    }

    // epilogue: C row = quad*4+reg, col = lane&15 (m89-verified, dtype-indep)
    if constexpr (EPI == 0) {
#pragma unroll
        for (int i = 0; i < 4; i++) {
            const int rowb = m0 + wm * 64 + i * 16 + quad * 4;
#pragma unroll
            for (int r = 0; r < 4; r++) {
                const size_t rr = (size_t)(rowb + r);
#pragma unroll
                for (int j = 0; j < 4; j++) {
                    const int cc = n0 + wn * 64 + j * 16 + l16;
                    float v = acc[i][j][r];
                    if (bias)  v += bias[cc];
                    if (resid) v += resid[rr * N + cc];
                    outf[rr * N + cc] = v;
                }
            }
        }
    } else {
        // SwiGLU fusion: j even = gate, j odd = up of same 16-col group.
        // Pair index = bn*4 + wn*2 + pjt -> col base = (n0>>1)+wn*32+pjt*16.
        const int NH = N >> 1;
#pragma unroll
        for (int i = 0; i < 4; i++) {
            const int rowb = m0 + wm * 64 + i * 16 + quad * 4;
#pragma unroll
            for (int r = 0; r < 4; r++) {
                const size_t rr = (size_t)(rowb + r);
#pragma unroll
                for (int pjt = 0; pjt < 2; pjt++) {
                    const float g = acc[i][2 * pjt][r];
                    const float u = acc[i][2 * pjt + 1][r];
                    const float a = (g / (1.0f + __expf(-g))) * u;
                    const int cc = (n0 >> 1) + wn * 32 + pjt * 16 + l16;
                    outh[rr * NH + cc] = f2h(a);
                }
            }
        }
    }
}

// ---------------------------------------------------------------------------
// RoPE prep Q: qkv fp32 -> fp16 [(b*16+h)*1024+s][128], scaled by 1/sqrt(hd).
// ---------------------------------------------------------------------------
__global__ __launch_bounds__(256)
void rope_q_kernel(const float* __restrict__ qkv, const int* __restrict__ offp,
                   uint16_t* __restrict__ Qb)
{
    const int idx = blockIdx.x * 256 + threadIdx.x;   // ROWS*16*64
    const int d   = idx & 63;
    const int h   = (idx >> 6) & 15;
    const int row = idx >> 10;
    const int b   = row >> 10;
    const int s   = row & (SEQ - 1);
    const float pos  = (float)(s + *offp);
    const float freq = powf(1.0e6f, -(float)d * (1.0f / 64.0f));
    float sn, cs;
    sincosf(pos * freq, &sn, &cs);
    const size_t gb = (size_t)row * N_QKV + h * HD + d;
    const float x1 = qkv[gb];
    const float x2 = qkv[gb + 64];
    const float qscale = 0.08838834764831845f;   // 1/sqrt(128)
    const size_t ob = ((size_t)(b * 16 + h) * SEQ + s) * HD + d;
    Qb[ob]      = f2h((x1 * cs - x2 * sn) * qscale);
    Qb[ob + 64] = f2h((x2 * cs + x1 * sn) * qscale);
}

// RoPE prep K: qkv fp32 -> fp16 [(b*4+kvh)*1024+s][128], unscaled.
__global__ __launch_bounds__(256)
void rope_k_kernel(const float* __restrict__ qkv, const int* __restrict__ offp,
                   uint16_t* __restrict__ Kb)
{
    const int idx = blockIdx.x * 256 + threadIdx.x;   // ROWS*4*64
    const int d   = idx & 63;
    const int kvh = (idx >> 6) & 3;
    const int row = idx >> 8;
    const int b   = row >> 10;
    const int s   = row & (SEQ - 1);
    const float pos  = (float)(s + *offp);
    const float freq = powf(1.0e6f, -(float)d * (1.0f / 64.0f));
    float sn, cs;
    sincosf(pos * freq, &sn, &cs);
    const size_t gb = (size_t)row * N_QKV + 2048 + kvh * HD + d;
    const float x1 = qkv[gb];
    const float x2 = qkv[gb + 64];
    const size_t ob = ((size_t)(b * 4 + kvh) * SEQ + s) * HD + d;
    Kb[ob]      = f2h(x1 * cs - x2 * sn);
    Kb[ob + 64] = f2h(x2 * cs + x1 * sn);
}

// V transpose prep: qkv fp32 -> fp16 V^T [(b*4+kvh)*128+dim][1024 keys].
// Block = 64 keys x 128 dims = 2048 float4s -> 8 iters of 256 threads.
__global__ __launch_bounds__(256)
void prep_v_kernel(const float* __restrict__ qkv, uint16_t* __restrict__ Vt)
{
    __shared__ uint16_t sh[128 * 72];
    const int tid = threadIdx.x;
    const int sc  = blockIdx.x & 15;     // 16 chunks of 64 keys
    const int bk  = blockIdx.x >> 4;     // b*4+kvh
    const int b   = bk >> 2, kvh = bk & 3;
#pragma unroll
    for (int p = 0; p < 8; p++) {
        const int q4 = p * 256 + tid;    // 2048 float4s: 64 rows x 32
        const int sloc = q4 >> 5, d4 = (q4 & 31) * 4;
        const float4 v = *reinterpret_cast<const float4*>(
            &qkv[(size_t)(b * SEQ + sc * 64 + sloc) * N_QKV + 2560 + kvh * HD + d4]);
        sh[(d4 + 0) * 72 + sloc] = f2h(v.x);
        sh[(d4 + 1) * 72 + sloc] = f2h(v.y);
        sh[(d4 + 2) * 72 + sloc] = f2h(v.z);
        sh[(d4 + 3) * 72 + sloc] = f2h(v.w);
    }
    __syncthreads();
    const int d = tid >> 1, half = tid & 1;
    const size_t ob = ((size_t)(bk * 128 + d)) * SEQ + sc * 64 + half * 32;
    const uint16_t* srh = &sh[d * 72 + half * 32];
#pragma unroll
    for (int k = 0; k < 4; k++)
        *reinterpret_cast<uint4*>(&Vt[ob + k * 8]) =
            *reinterpret_cast<const uint4*>(&srh[k * 8]);
}

// ---------------------------------------------------------------------------
// MFMA fp16 flash attention. Block = 64 Q rows of one (b,h); 4 waves x 16 rows.
// 32-key tiles: K [32][128] (XOR-swizzled granules), V^T [128][32],
// P [wave][16][32] contiguous. Online softmax per-lane (C-layout rows).
// Output fp16 [row][h*128+d].
// ---------------------------------------------------------------------------
__global__ __launch_bounds__(256)
void attn_kernel(const uint16_t* __restrict__ Qb, const uint16_t* __restrict__ Kb,
                 const uint16_t* __restrict__ Vt, uint16_t* __restrict__ att)
{
    __shared__ uint16_t sK[32 * 128];
    __shared__ uint16_t sV[128 * 32];
    __shared__ uint16_t sP[4 * 16 * 32];

    const int tid  = threadIdx.x;
    const int lane = tid & 63;
    const int wv   = tid >> 6;
    const int quad = lane >> 4;
    const int l16  = lane & 15;

    const int bi  = blockIdx.x;
    const int sc  = 15 - (bi >> 5);      // big Q-tiles dispatched first
    const int bh  = bi & 31;
    const int b   = bh >> 4;
    const int h   = bh & 15;
    const int kvh = h >> 2;
    const int s0  = sc << 6;

    // Q fragments (A-layout) straight from global, once.
    f16x8 qf[4];
    {
        const size_t qb = ((size_t)(b * 16 + h) * SEQ + s0 + wv * 16 + l16) * HD;
#pragma unroll
        for (int ks = 0; ks < 4; ks++)
            qf[ks] = *reinterpret_cast<const f16x8*>(&Qb[qb + ks * 32 + quad * 8]);
    }

    float m_i[4], l_i[4];
#pragma unroll
    for (int r = 0; r < 4; r++) { m_i[r] = -1e30f; l_i[r] = 0.f; }
    f32x4 oacc[8];
#pragma unroll
    for (int dt = 0; dt < 8; dt++) oacc[dt] = (f32x4){0.f, 0.f, 0.f, 0.f};

    const size_t kb = (size_t)(b * 4 + kvh) * SEQ * HD;        // K base (elems)
    const size_t vb = (size_t)(b * 4 + kvh) * HD * SEQ;        // V^T base

    const int ntiles = 2 * sc + 2;
    for (int tt = 0; tt < ntiles; tt++) {
        const int t0 = tt << 5;
        __syncthreads();
        // stage K (swizzled source) and V^T
#pragma unroll
        for (int p = 0; p < 2; p++) {
            const int cb = p * 256 + wv * 64;
            const int c  = cb + lane;
            const int krow = c >> 4;
            const int kcc  = (c & 15) ^ (krow & 7);
            async_load16(Kb + kb + (size_t)(t0 + krow) * HD + kcc * 8, &sK[cb * 8]);
            const int vrow = c >> 2;
            const int vcc  = c & 3;
            async_load16(Vt + vb + (size_t)vrow * SEQ + t0 + vcc * 8, &sV[cb * 8]);
        }
        __syncthreads();

        // S = Q·K^T
        f32x4 sacc[2];
        sacc[0] = (f32x4){0.f, 0.f, 0.f, 0.f};
        sacc[1] = (f32x4){0.f, 0.f, 0.f, 0.f};
#pragma unroll
        for (int ks = 0; ks < 4; ks++) {
#pragma unroll
            for (int jt = 0; jt < 2; jt++) {
                const int idx = (jt * 16 + l16) * 128 + (((ks * 4 + quad) ^ (l16 & 7)) * 8);
                const f16x8 kf = *reinterpret_cast<const f16x8*>(&sK[idx]);
                sacc[jt] = __builtin_amdgcn_mfma_f32_16x16x32_f16(qf[ks], kf, sacc[jt], 0, 0, 0);
            }
        }

        // causal mask (only diagonal-region tiles)
        if (t0 >= s0) {
            const int rowg = s0 + wv * 16 + quad * 4;
#pragma unroll
            for (int jt = 0; jt < 2; jt++) {
                const int key = t0 + jt * 16 + l16;
#pragma unroll
                for (int r = 0; r < 4; r++)
                    if (key > rowg + r) sacc[jt][r] = -1e30f;
            }
        }

        // online softmax per reg (rows quad*4+reg; reduce over 16 l16 lanes)
        float alpha[4];
#pragma unroll
        for (int r = 0; r < 4; r++) {
            float mt = fmaxf(sacc[0][r], sacc[1][r]);
#pragma unroll
            for (int off = 8; off; off >>= 1) mt = fmaxf(mt, __shfl_xor(mt, off));
            const float mn = fmaxf(m_i[r], mt);
            alpha[r] = __expf(m_i[r] - mn);
            const float p0 = __expf(sacc[0][r] - mn);
            const float p1 = __expf(sacc[1][r] - mn);
            float ps = p0 + p1;
#pragma unroll
            for (int off = 8; off; off >>= 1) ps += __shfl_xor(ps, off);
            l_i[r] = l_i[r] * alpha[r] + ps;
            m_i[r] = mn;
            // write P: wave-private block, row = quad*4+r, key = jt*16+l16
            const int prow = quad * 4 + r;
            sP[wv * 512 + prow * 32 + 0 * 16 + l16] = f2h(p0);
            sP[wv * 512 + prow * 32 + 1 * 16 + l16] = f2h(p1);
        }
        __syncthreads();

        // rescale O by alpha, then PV
#pragma unroll
        for (int dt = 0; dt < 8; dt++) {
#pragma unroll
            for (int r = 0; r < 4; r++) oacc[dt][r] *= alpha[r];
        }
        const f16x8 pf = *reinterpret_cast<const f16x8*>(&sP[wv * 512 + l16 * 32 + quad * 8]);
#pragma unroll
        for (int dt = 0; dt < 8; dt++) {
            const f16x8 vf = *reinterpret_cast<const f16x8*>(&sV[(dt * 16 + l16) * 32 + quad * 8]);
            oacc[dt] = __builtin_amdgcn_mfma_f32_16x16x32_f16(pf, vf, oacc[dt], 0, 0, 0);
        }
    }

    // final normalize + store (C-layout rows)
    float inv[4];
#pragma unroll
    for (int r = 0; r < 4; r++) inv[r] = 1.0f / l_i[r];
#pragma unroll
    for (int r = 0; r < 4; r++) {
        const size_t rowg = (size_t)(b * SEQ + s0 + wv * 16 + quad * 4 + r);
#pragma unroll
        for (int dt = 0; dt < 8; dt++)
            att[rowg * D_MODEL + h * HD + dt * 16 + l16] = f2h(oacc[dt][r] * inv[r]);
    }
}

// ---------------------------------------------------------------------------
extern "C" void kernel_launch(void* const* d_in, const int* in_sizes, int n_in,
                              void* d_out, int out_size, void* d_ws, size_t ws_size,
                              hipStream_t stream)
{
    (void)in_sizes; (void)n_in; (void)out_size; (void)ws_size;
    const float* x      = (const float*)d_in[0];
    const int*   wq_q   = (const int*)d_in[1];
    const float* wq_s   = (const float*)d_in[2];
    const float* bq     = (const float*)d_in[3];
    const int*   wk_q   = (const int*)d_in[4];
    const float* wk_s   = (const float*)d_in[5];
    const float* bk     = (const float*)d_in[6];
    const int*   wv_q   = (const int*)d_in[7];
    const float* wv_s   = (const float*)d_in[8];
    const float* bv     = (const float*)d_in[9];
    const int*   wo_q   = (const int*)d_in[10];
    const float* wo_s   = (const float*)d_in[11];
    const int*   gate_q = (const int*)d_in[12];
    const float* gate_s = (const float*)d_in[13];
    const int*   up_q   = (const int*)d_in[14];
    const float* up_s   = (const float*)d_in[15];
    const int*   down_q = (const int*)d_in[16];
    const float* down_s = (const float*)d_in[17];
    const float* w_in   = (const float*)d_in[18];
    const float* w_post = (const float*)d_in[19];
    const int*   offp   = (const int*)d_in[20];

    char* p = (char*)d_ws;
    auto alloc = [&](size_t bytes) {
        char* r = p;
        p += (bytes + 255) & ~(size_t)255;
        return r;
    };
    // persistent
    uint16_t* Wgu   = (uint16_t*)alloc((size_t)2 * D_FF * D_MODEL * 2);  // 46.1 MB
    uint16_t* Wdown = (uint16_t*)alloc((size_t)D_MODEL * D_FF * 2);      // 23.1 MB
    uint16_t* hbuf  = (uint16_t*)alloc((size_t)ROWS * D_MODEL * 2);      // h / h2
    float*    x2    = (float*)alloc((size_t)ROWS * D_MODEL * 4);
    float*    bqkv  = (float*)alloc((size_t)N_QKV * 4);
    // transient zone: Wqkv | Wo | qkv fp32  (aliased later)
    char* zone = alloc((size_t)N_QKV * D_MODEL * 2 +
                       (size_t)D_MODEL * D_MODEL * 2 +
                       (size_t)ROWS * N_QKV * 4 + 8192);
    uint16_t* Wqkv = (uint16_t*)zone;
    uint16_t* Wo   = Wqkv + (size_t)N_QKV * D_MODEL;
    float*    qkv  = (float*)(Wo + (size_t)D_MODEL * D_MODEL);
    // prep buffers alias Wqkv (dead after QKV GEMM): Q 8.39 + K 2.10 + V 2.10
    // = 12.58 MB = exactly sizeof(Wqkv).
    uint16_t* Qb = Wqkv;
    uint16_t* Kb = Qb + (size_t)BATCH * 16 * SEQ * HD;
    uint16_t* Vt = Kb + (size_t)BATCH * 4 * SEQ * HD;
    // attention output aliases qkv (dead after preps)
    uint16_t* att = (uint16_t*)qkv;
    // act aliases zone start (Wqkv/Wo/att all dead after O-proj); 23.1 MB
    uint16_t* act = (uint16_t*)zone;

    auto dq = [&](const int* q, const float* s, uint16_t* o,
                  size_t n, int I, int mode) {
        const int n4 = (int)(n / 4);
        dequant_kernel<<<(n4 + 255) / 256, 256, 0, stream>>>(q, s, o, n4, I, mode);
    };
    dq(wq_q, wq_s, Wqkv, (size_t)2048 * 2048, 2048, 0);
    dq(wk_q, wk_s, Wqkv + (size_t)2048 * 2048, (size_t)512 * 2048, 2048, 0);
    dq(wv_q, wv_s, Wqkv + (size_t)2560 * 2048, (size_t)512 * 2048, 2048, 0);
    dq(wo_q, wo_s, Wo, (size_t)2048 * 2048, 2048, 0);
    dq(gate_q, gate_s, Wgu, (size_t)D_FF * 2048, 2048, 1);
    dq(up_q, up_s, Wgu, (size_t)D_FF * 2048, 2048, 2);
    dq(down_q, down_s, Wdown, (size_t)2048 * D_FF, D_FF, 0);

    biascat_kernel<<<(N_QKV + 255) / 256, 256, 0, stream>>>(bq, bk, bv, bqkv);
    rmsnorm_kernel<<<ROWS, 256, 0, stream>>>(x, w_in, hbuf);

    gemm_f16_kernel<0><<<(ROWS / 128) * (N_QKV / 128), 256, 0, stream>>>(
        hbuf, Wqkv, bqkv, nullptr, qkv, nullptr, ROWS, N_QKV, D_MODEL);

    rope_q_kernel<<<(ROWS * 16 * 64) / 256, 256, 0, stream>>>(qkv, offp, Qb);
    rope_k_kernel<<<(ROWS * 4 * 64) / 256, 256, 0, stream>>>(qkv, offp, Kb);
    prep_v_kernel<<<BATCH * 4 * (SEQ / 64), 256, 0, stream>>>(qkv, Vt);

    attn_kernel<<<BATCH * HEADS * (SEQ / 64), 256, 0, stream>>>(Qb, Kb, Vt, att);

    gemm_f16_kernel<0><<<(ROWS / 128) * (D_MODEL / 128), 256, 0, stream>>>(
        att, Wo, nullptr, x, x2, nullptr, ROWS, D_MODEL, D_MODEL);

    rmsnorm_kernel<<<ROWS, 256, 0, stream>>>(x2, w_post, hbuf);

    gemm_f16_kernel<2><<<(ROWS / 128) * (2 * D_FF / 128), 256, 0, stream>>>(
        hbuf, Wgu, nullptr, nullptr, nullptr, act, ROWS, 2 * D_FF, D_MODEL);

    gemm_f16_kernel<0><<<(ROWS / 128) * (D_MODEL / 128), 256, 0, stream>>>(
        act, Wdown, nullptr, x2, (float*)d_out, nullptr, ROWS, D_MODEL, D_FF);
}

// Round 7
// 677.307 us; speedup vs baseline: 1.9660x; 1.0687x over previous
//
#include <hip/hip_runtime.h>
#include <cstdint>
#include <cstddef>

#define DEV __device__ __forceinline__

typedef _Float16 f16x8 __attribute__((ext_vector_type(8)));
typedef float f32x4 __attribute__((ext_vector_type(4)));

static constexpr int D_MODEL = 2048;
static constexpr int D_FF    = 5632;
static constexpr int N_QKV   = 3072;   // 2048 q + 512 k + 512 v
static constexpr int SEQ     = 1024;
static constexpr int BATCH   = 2;
static constexpr int ROWS    = BATCH * SEQ;  // 2048
static constexpr int HEADS   = 16;
static constexpr int HD      = 128;

DEV uint16_t f2h(float f) {
    return __builtin_bit_cast(uint16_t, (_Float16)f);   // RTNE, 2^-12 RMS rel err
}
DEV float h2f(uint16_t u) {
    return (float)__builtin_bit_cast(_Float16, u);
}

// async global->LDS, 16B/lane; lds ptr must be wave-uniform (HW adds lane*16)
DEV void async_load16(const void* g, void* lds) {
    __builtin_amdgcn_global_load_lds(
        reinterpret_cast<__attribute__((address_space(1))) void*>(
            reinterpret_cast<uintptr_t>(g)),
        reinterpret_cast<__attribute__((address_space(3))) void*>(
            static_cast<uint32_t>(reinterpret_cast<uintptr_t>(lds))),
        16, 0, 0);
}

// ---------------------------------------------------------------------------
// Dequant to fp16: w = q*s (fp32) -> _Float16 (rel err 2^-12).
// mode 0: orow=row; mode 1: gate interleave; mode 2: up interleave.
// ---------------------------------------------------------------------------
__global__ __launch_bounds__(256)
void dequant_kernel(const int* __restrict__ q, const float* __restrict__ s,
                    uint16_t* __restrict__ wout, int n4, int I, int mode)
{
    const int idx = blockIdx.x * 256 + threadIdx.x;
    if (idx >= n4) return;
    const int e = idx * 4;
    const int row = e / I;
    const int i = e - row * I;
    const int4 qv = *reinterpret_cast<const int4*>(&q[e]);
    const float scf = s[row * (I >> 6) + (i >> 6)];
    int orow = row;
    if (mode == 1) orow = ((row >> 4) << 5) + (row & 15);
    else if (mode == 2) orow = ((row >> 4) << 5) + (row & 15) + 16;
    uint16_t h[4];
    h[0] = f2h((float)qv.x * scf);
    h[1] = f2h((float)qv.y * scf);
    h[2] = f2h((float)qv.z * scf);
    h[3] = f2h((float)qv.w * scf);
    uint2 pk;
    pk.x = (uint32_t)h[0] | ((uint32_t)h[1] << 16);
    pk.y = (uint32_t)h[2] | ((uint32_t)h[3] << 16);
    *reinterpret_cast<uint2*>(&wout[(size_t)orow * I + i]) = pk;
}

__global__ __launch_bounds__(256)
void biascat_kernel(const float* __restrict__ bq, const float* __restrict__ bk,
                    const float* __restrict__ bv, float* __restrict__ out)
{
    const int i = blockIdx.x * 256 + threadIdx.x;
    if (i >= N_QKV) return;
    float v;
    if (i < 2048)      v = bq[i];
    else if (i < 2560) v = bk[i - 2048];
    else               v = bv[i - 2560];
    out[i] = v;
}

// ---------------------------------------------------------------------------
// RMSNorm (fp32 in) -> fp16. One row (2048) per block of 256.
// ---------------------------------------------------------------------------
__global__ __launch_bounds__(256)
void rmsnorm_kernel(const float* __restrict__ x, const float* __restrict__ wln,
                    uint16_t* __restrict__ out)
{
    __shared__ float red[4];
    const int row = blockIdx.x;
    const int tid = threadIdx.x;
    const float* xr = x + (size_t)row * D_MODEL;
    const float4 v0 = *reinterpret_cast<const float4*>(&xr[tid * 8]);
    const float4 v1 = *reinterpret_cast<const float4*>(&xr[tid * 8 + 4]);
    float ss = v0.x*v0.x + v0.y*v0.y + v0.z*v0.z + v0.w*v0.w
             + v1.x*v1.x + v1.y*v1.y + v1.z*v1.z + v1.w*v1.w;
#pragma unroll
    for (int off = 32; off; off >>= 1) ss += __shfl_xor(ss, off);
    if ((tid & 63) == 0) red[tid >> 6] = ss;
    __syncthreads();
    const float rms = rsqrtf((red[0] + red[1] + red[2] + red[3]) * (1.0f / D_MODEL) + 1e-6f);
    const int cb = tid * 8;
    const size_t base = (size_t)row * D_MODEL + cb;
    const float vals[8] = {v0.x, v0.y, v0.z, v0.w, v1.x, v1.y, v1.z, v1.w};
#pragma unroll
    for (int k = 0; k < 8; k += 2) {
        const uint16_t h0 = f2h(vals[k] * rms * wln[cb + k]);
        const uint16_t h1 = f2h(vals[k + 1] * rms * wln[cb + k + 1]);
        *reinterpret_cast<uint32_t*>(&out[base + k]) = (uint32_t)h0 | ((uint32_t)h1 << 16);
    }
}

// ---------------------------------------------------------------------------
// fp16 GEMM, 128x128 tile (EPI 2 = fused SwiGLU, gate/up interleaved W).
// BK=32, 4 waves 2x2, wave 4x4 MFMA 16x16x32 f16.
// ---------------------------------------------------------------------------
__global__ __launch_bounds__(256)
void gemm_f16_glu_kernel(const uint16_t* __restrict__ A, const uint16_t* __restrict__ W,
                         uint16_t* __restrict__ outh, int M, int N, int K)
{
    __shared__ uint16_t sA[128 * 32];
    __shared__ uint16_t sB[128 * 32];

    const int tid  = threadIdx.x;
    const int lane = tid & 63;
    const int wv   = tid >> 6;
    const int wm   = wv >> 1;
    const int wn   = wv & 1;
    const int quad = lane >> 4;
    const int l16  = lane & 15;

    const int nBn = N >> 7;
    const int bm  = blockIdx.x / nBn;
    const int bn  = blockIdx.x - bm * nBn;
    const int m0  = bm << 7;
    const int n0  = bn << 7;

    f32x4 acc[4][4];
#pragma unroll
    for (int i = 0; i < 4; i++)
#pragma unroll
        for (int j = 0; j < 4; j++)
            acc[i][j] = (f32x4){0.f, 0.f, 0.f, 0.f};

    const uint16_t* Ab = A + (size_t)m0 * K;
    const uint16_t* Wb = W + (size_t)n0 * K;

    for (int kt = 0; kt < K; kt += 32) {
        __syncthreads();
#pragma unroll
        for (int p = 0; p < 2; p++) {
            const int cb = p * 256 + wv * 64;          // wave-uniform chunk base
            const int c  = cb + lane;
            const int row = c >> 2, e = (c & 3) * 8;
            const size_t goff = (size_t)row * K + kt + e;
            async_load16(Ab + goff, &sA[cb * 8]);
            async_load16(Wb + goff, &sB[cb * 8]);
        }
        __syncthreads();

        f16x8 bf[4];
#pragma unroll
        for (int j = 0; j < 4; j++)
            bf[j] = *reinterpret_cast<const f16x8*>(
                &sB[(wn * 64 + j * 16 + l16) * 32 + quad * 8]);
#pragma unroll
        for (int i = 0; i < 4; i++) {
            const f16x8 af = *reinterpret_cast<const f16x8*>(
                &sA[(wm * 64 + i * 16 + l16) * 32 + quad * 8]);
#pragma unroll
            for (int j = 0; j < 4; j++)
                acc[i][j] = __builtin_amdgcn_mfma_f32_16x16x32_f16(af, bf[j], acc[i][j], 0, 0, 0);
        }
    }

    // SwiGLU: j even = gate, j odd = up of same 16-col group.
    // Pair index = bn*4 + wn*2 + pjt -> col base = (n0>>1)+wn*32+pjt*16.
    const int NH = N >> 1;
#pragma unroll
    for (int i = 0; i < 4; i++) {
        const int rowb = m0 + wm * 64 + i * 16 + quad * 4;
#pragma unroll
        for (int r = 0; r < 4; r++) {
            const size_t rr = (size_t)(rowb + r);
#pragma unroll
            for (int pjt = 0; pjt < 2; pjt++) {
                const float g = acc[i][2 * pjt][r];
                const float u = acc[i][2 * pjt + 1][r];
                const float a = (g / (1.0f + __expf(-g))) * u;
                const int cc = (n0 >> 1) + wn * 32 + pjt * 16 + l16;
                outh[rr * NH + cc] = f2h(a);
            }
        }
    }
}

// ---------------------------------------------------------------------------
// fp16 GEMM, 64x128 tile (fp32 out, +bias/+resid). BK=32. 4 waves side-by-side
// along N: wave = rows 0..63 x cols wv*32..wv*32+31, acc[4][2].
// Doubles grid size vs 128-tile -> 2-3 blocks/CU on the square GEMMs
// (round-6 profile: 256-block grids ran at MfmaUtil 12%, 1 block/CU).
// ---------------------------------------------------------------------------
__global__ __launch_bounds__(256)
void gemm_f16_m64_kernel(const uint16_t* __restrict__ A, const uint16_t* __restrict__ W,
                         const float* __restrict__ bias, const float* __restrict__ resid,
                         float* __restrict__ outf, int M, int N, int K)
{
    __shared__ uint16_t sA[64 * 32];
    __shared__ uint16_t sB[128 * 32];

    const int tid  = threadIdx.x;
    const int lane = tid & 63;
    const int wv   = tid >> 6;
    const int quad = lane >> 4;
    const int l16  = lane & 15;

    const int nBn = N >> 7;
    const int bm  = blockIdx.x / nBn;
    const int bn  = blockIdx.x - bm * nBn;
    const int m0  = bm << 6;
    const int n0  = bn << 7;

    f32x4 acc[4][2];
#pragma unroll
    for (int i = 0; i < 4; i++)
#pragma unroll
        for (int j = 0; j < 2; j++)
            acc[i][j] = (f32x4){0.f, 0.f, 0.f, 0.f};

    const uint16_t* Ab = A + (size_t)m0 * K;
    const uint16_t* Wb = W + (size_t)n0 * K;

    for (int kt = 0; kt < K; kt += 32) {
        __syncthreads();
        {   // A tile: 256 chunks, 1/thread
            const int cb = wv * 64;
            const int c  = cb + lane;
            const int row = c >> 2, e = (c & 3) * 8;
            async_load16(Ab + (size_t)row * K + kt + e, &sA[cb * 8]);
        }
#pragma unroll
        for (int p = 0; p < 2; p++) {   // B tile: 512 chunks, 2/thread
            const int cb = p * 256 + wv * 64;
            const int c  = cb + lane;
            const int row = c >> 2, e = (c & 3) * 8;
            async_load16(Wb + (size_t)row * K + kt + e, &sB[cb * 8]);
        }
        __syncthreads();

        f16x8 bf[2];
#pragma unroll
        for (int j = 0; j < 2; j++)
            bf[j] = *reinterpret_cast<const f16x8*>(
                &sB[(wv * 32 + j * 16 + l16) * 32 + quad * 8]);
#pragma unroll
        for (int i = 0; i < 4; i++) {
            const f16x8 af = *reinterpret_cast<const f16x8*>(
                &sA[(i * 16 + l16) * 32 + quad * 8]);
#pragma unroll
            for (int j = 0; j < 2; j++)
                acc[i][j] = __builtin_amdgcn_mfma_f32_16x16x32_f16(af, bf[j], acc[i][j], 0, 0, 0);
        }
    }

    // epilogue: C row = quad*4+reg, col = lane&15 (m89-verified, dtype-indep)
#pragma unroll
    for (int i = 0; i < 4; i++) {
        const int rowb = m0 + i * 16 + quad * 4;
#pragma unroll
        for (int r = 0; r < 4; r++) {
            const size_t rr = (size_t)(rowb + r);
#pragma unroll
            for (int j = 0; j < 2; j++) {
                const int cc = n0 + wv * 32 + j * 16 + l16;
                float v = acc[i][j][r];
                if (bias)  v += bias[cc];
                if (resid) v += resid[rr * N + cc];
                outf[rr * N + cc] = v;
            }
        }
    }
}

// ---------------------------------------------------------------------------
// RoPE prep Q: qkv fp32 -> fp16 [(b*16+h)*1024+s][128], scaled by 1/sqrt(hd).
// ---------------------------------------------------------------------------
__global__ __launch_bounds__(256)
void rope_q_kernel(const float* __restrict__ qkv, const int* __restrict__ offp,
                   uint16_t* __restrict__ Qb)
{
    const int idx = blockIdx.x * 256 + threadIdx.x;   // ROWS*16*64
    const int d   = idx & 63;
    const int h   = (idx >> 6) & 15;
    const int row = idx >> 10;
    const int b   = row >> 10;
    const int s   = row & (SEQ - 1);
    const float pos  = (float)(s + *offp);
    const float freq = powf(1.0e6f, -(float)d * (1.0f / 64.0f));
    float sn, cs;
    sincosf(pos * freq, &sn, &cs);
    const size_t gb = (size_t)row * N_QKV + h * HD + d;
    const float x1 = qkv[gb];
    const float x2 = qkv[gb + 64];
    const float qscale = 0.08838834764831845f;   // 1/sqrt(128)
    const size_t ob = ((size_t)(b * 16 + h) * SEQ + s) * HD + d;
    Qb[ob]      = f2h((x1 * cs - x2 * sn) * qscale);
    Qb[ob + 64] = f2h((x2 * cs + x1 * sn) * qscale);
}

// RoPE prep K: qkv fp32 -> fp16 [(b*4+kvh)*1024+s][128], unscaled.
__global__ __launch_bounds__(256)
void rope_k_kernel(const float* __restrict__ qkv, const int* __restrict__ offp,
                   uint16_t* __restrict__ Kb)
{
    const int idx = blockIdx.x * 256 + threadIdx.x;   // ROWS*4*64
    const int d   = idx & 63;
    const int kvh = (idx >> 6) & 3;
    const int row = idx >> 8;
    const int b   = row >> 10;
    const int s   = row & (SEQ - 1);
    const float pos  = (float)(s + *offp);
    const float freq = powf(1.0e6f, -(float)d * (1.0f / 64.0f));
    float sn, cs;
    sincosf(pos * freq, &sn, &cs);
    const size_t gb = (size_t)row * N_QKV + 2048 + kvh * HD + d;
    const float x1 = qkv[gb];
    const float x2 = qkv[gb + 64];
    const size_t ob = ((size_t)(b * 4 + kvh) * SEQ + s) * HD + d;
    Kb[ob]      = f2h(x1 * cs - x2 * sn);
    Kb[ob + 64] = f2h(x2 * cs + x1 * sn);
}

// V transpose prep: qkv fp32 -> fp16 V^T [(b*4+kvh)*128+dim][1024 keys].
// Block = 64 keys x 128 dims = 2048 float4s -> 8 iters of 256 threads.
__global__ __launch_bounds__(256)
void prep_v_kernel(const float* __restrict__ qkv, uint16_t* __restrict__ Vt)
{
    __shared__ uint16_t sh[128 * 72];
    const int tid = threadIdx.x;
    const int sc  = blockIdx.x & 15;     // 16 chunks of 64 keys
    const int bk  = blockIdx.x >> 4;     // b*4+kvh
    const int b   = bk >> 2, kvh = bk & 3;
#pragma unroll
    for (int p = 0; p < 8; p++) {
        const int q4 = p * 256 + tid;    // 2048 float4s: 64 rows x 32
        const int sloc = q4 >> 5, d4 = (q4 & 31) * 4;
        const float4 v = *reinterpret_cast<const float4*>(
            &qkv[(size_t)(b * SEQ + sc * 64 + sloc) * N_QKV + 2560 + kvh * HD + d4]);
        sh[(d4 + 0) * 72 + sloc] = f2h(v.x);
        sh[(d4 + 1) * 72 + sloc] = f2h(v.y);
        sh[(d4 + 2) * 72 + sloc] = f2h(v.z);
        sh[(d4 + 3) * 72 + sloc] = f2h(v.w);
    }
    __syncthreads();
    const int d = tid >> 1, half = tid & 1;
    const size_t ob = ((size_t)(bk * 128 + d)) * SEQ + sc * 64 + half * 32;
    const uint16_t* srh = &sh[d * 72 + half * 32];
#pragma unroll
    for (int k = 0; k < 4; k++)
        *reinterpret_cast<uint4*>(&Vt[ob + k * 8]) =
            *reinterpret_cast<const uint4*>(&srh[k * 8]);
}

// ---------------------------------------------------------------------------
// MFMA fp16 flash attention. Block = 64 Q rows of one (b,h); 4 waves x 16 rows.
// 32-key tiles: K [32][128] (XOR-swizzled granules), V^T [128][32],
// P [wave][16][32] contiguous. Online softmax per-lane (C-layout rows).
// Output fp16 [row][h*128+d].
// ---------------------------------------------------------------------------
__global__ __launch_bounds__(256)
void attn_kernel(const uint16_t* __restrict__ Qb, const uint16_t* __restrict__ Kb,
                 const uint16_t* __restrict__ Vt, uint16_t* __restrict__ att)
{
    __shared__ uint16_t sK[32 * 128];
    __shared__ uint16_t sV[128 * 32];
    __shared__ uint16_t sP[4 * 16 * 32];

    const int tid  = threadIdx.x;
    const int lane = tid & 63;
    const int wv   = tid >> 6;
    const int quad = lane >> 4;
    const int l16  = lane & 15;

    const int bi  = blockIdx.x;
    const int sc  = 15 - (bi >> 5);      // big Q-tiles dispatched first
    const int bh  = bi & 31;
    const int b   = bh >> 4;
    const int h   = bh & 15;
    const int kvh = h >> 2;
    const int s0  = sc << 6;

    // Q fragments (A-layout) straight from global, once.
    f16x8 qf[4];
    {
        const size_t qb = ((size_t)(b * 16 + h) * SEQ + s0 + wv * 16 + l16) * HD;
#pragma unroll
        for (int ks = 0; ks < 4; ks++)
            qf[ks] = *reinterpret_cast<const f16x8*>(&Qb[qb + ks * 32 + quad * 8]);
    }

    float m_i[4], l_i[4];
#pragma unroll
    for (int r = 0; r < 4; r++) { m_i[r] = -1e30f; l_i[r] = 0.f; }
    f32x4 oacc[8];
#pragma unroll
    for (int dt = 0; dt < 8; dt++) oacc[dt] = (f32x4){0.f, 0.f, 0.f, 0.f};

    const size_t kb = (size_t)(b * 4 + kvh) * SEQ * HD;        // K base (elems)
    const size_t vb = (size_t)(b * 4 + kvh) * HD * SEQ;        // V^T base

    const int ntiles = 2 * sc + 2;
    for (int tt = 0; tt < ntiles; tt++) {
        const int t0 = tt << 5;
        __syncthreads();
        // stage K (swizzled source) and V^T
#pragma unroll
        for (int p = 0; p < 2; p++) {
            const int cb = p * 256 + wv * 64;
            const int c  = cb + lane;
            const int krow = c >> 4;
            const int kcc  = (c & 15) ^ (krow & 7);
            async_load16(Kb + kb + (size_t)(t0 + krow) * HD + kcc * 8, &sK[cb * 8]);
            const int vrow = c >> 2;
            const int vcc  = c & 3;
            async_load16(Vt + vb + (size_t)vrow * SEQ + t0 + vcc * 8, &sV[cb * 8]);
        }
        __syncthreads();

        // S = Q·K^T
        f32x4 sacc[2];
        sacc[0] = (f32x4){0.f, 0.f, 0.f, 0.f};
        sacc[1] = (f32x4){0.f, 0.f, 0.f, 0.f};
#pragma unroll
        for (int ks = 0; ks < 4; ks++) {
#pragma unroll
            for (int jt = 0; jt < 2; jt++) {
                const int idx = (jt * 16 + l16) * 128 + (((ks * 4 + quad) ^ (l16 & 7)) * 8);
                const f16x8 kf = *reinterpret_cast<const f16x8*>(&sK[idx]);
                sacc[jt] = __builtin_amdgcn_mfma_f32_16x16x32_f16(qf[ks], kf, sacc[jt], 0, 0, 0);
            }
        }

        // causal mask (only diagonal-region tiles)
        if (t0 >= s0) {
            const int rowg = s0 + wv * 16 + quad * 4;
#pragma unroll
            for (int jt = 0; jt < 2; jt++) {
                const int key = t0 + jt * 16 + l16;
#pragma unroll
                for (int r = 0; r < 4; r++)
                    if (key > rowg + r) sacc[jt][r] = -1e30f;
            }
        }

        // online softmax per reg (rows quad*4+reg; reduce over 16 l16 lanes)
        float alpha[4];
#pragma unroll
        for (int r = 0; r < 4; r++) {
            float mt = fmaxf(sacc[0][r], sacc[1][r]);
#pragma unroll
            for (int off = 8; off; off >>= 1) mt = fmaxf(mt, __shfl_xor(mt, off));
            const float mn = fmaxf(m_i[r], mt);
            alpha[r] = __expf(m_i[r] - mn);
            const float p0 = __expf(sacc[0][r] - mn);
            const float p1 = __expf(sacc[1][r] - mn);
            float ps = p0 + p1;
#pragma unroll
            for (int off = 8; off; off >>= 1) ps += __shfl_xor(ps, off);
            l_i[r] = l_i[r] * alpha[r] + ps;
            m_i[r] = mn;
            // write P: wave-private block, row = quad*4+r, key = jt*16+l16
            const int prow = quad * 4 + r;
            sP[wv * 512 + prow * 32 + 0 * 16 + l16] = f2h(p0);
            sP[wv * 512 + prow * 32 + 1 * 16 + l16] = f2h(p1);
        }
        __syncthreads();

        // rescale O by alpha, then PV
#pragma unroll
        for (int dt = 0; dt < 8; dt++) {
#pragma unroll
            for (int r = 0; r < 4; r++) oacc[dt][r] *= alpha[r];
        }
        const f16x8 pf = *reinterpret_cast<const f16x8*>(&sP[wv * 512 + l16 * 32 + quad * 8]);
#pragma unroll
        for (int dt = 0; dt < 8; dt++) {
            const f16x8 vf = *reinterpret_cast<const f16x8*>(&sV[(dt * 16 + l16) * 32 + quad * 8]);
            oacc[dt] = __builtin_amdgcn_mfma_f32_16x16x32_f16(pf, vf, oacc[dt], 0, 0, 0);
        }
    }

    // final normalize + store (C-layout rows)
    float inv[4];
#pragma unroll
    for (int r = 0; r < 4; r++) inv[r] = 1.0f / l_i[r];
#pragma unroll
    for (int r = 0; r < 4; r++) {
        const size_t rowg = (size_t)(b * SEQ + s0 + wv * 16 + quad * 4 + r);
#pragma unroll
        for (int dt = 0; dt < 8; dt++)
            att[rowg * D_MODEL + h * HD + dt * 16 + l16] = f2h(oacc[dt][r] * inv[r]);
    }
}

// ---------------------------------------------------------------------------
extern "C" void kernel_launch(void* const* d_in, const int* in_sizes, int n_in,
                              void* d_out, int out_size, void* d_ws, size_t ws_size,
                              hipStream_t stream)
{
    (void)in_sizes; (void)n_in; (void)out_size; (void)ws_size;
    const float* x      = (const float*)d_in[0];
    const int*   wq_q   = (const int*)d_in[1];
    const float* wq_s   = (const float*)d_in[2];
    const float* bq     = (const float*)d_in[3];
    const int*   wk_q   = (const int*)d_in[4];
    const float* wk_s   = (const float*)d_in[5];
    const float* bk     = (const float*)d_in[6];
    const int*   wv_q   = (const int*)d_in[7];
    const float* wv_s   = (const float*)d_in[8];
    const float* bv     = (const float*)d_in[9];
    const int*   wo_q   = (const int*)d_in[10];
    const float* wo_s   = (const float*)d_in[11];
    const int*   gate_q = (const int*)d_in[12];
    const float* gate_s = (const float*)d_in[13];
    const int*   up_q   = (const int*)d_in[14];
    const float* up_s   = (const float*)d_in[15];
    const int*   down_q = (const int*)d_in[16];
    const float* down_s = (const float*)d_in[17];
    const float* w_in   = (const float*)d_in[18];
    const float* w_post = (const float*)d_in[19];
    const int*   offp   = (const int*)d_in[20];

    char* p = (char*)d_ws;
    auto alloc = [&](size_t bytes) {
        char* r = p;
        p += (bytes + 255) & ~(size_t)255;
        return r;
    };
    // persistent
    uint16_t* Wgu   = (uint16_t*)alloc((size_t)2 * D_FF * D_MODEL * 2);  // 46.1 MB
    uint16_t* Wdown = (uint16_t*)alloc((size_t)D_MODEL * D_FF * 2);      // 23.1 MB
    uint16_t* hbuf  = (uint16_t*)alloc((size_t)ROWS * D_MODEL * 2);      // h / h2
    float*    x2    = (float*)alloc((size_t)ROWS * D_MODEL * 4);
    float*    bqkv  = (float*)alloc((size_t)N_QKV * 4);
    // transient zone: Wqkv | Wo | qkv fp32  (aliased later)
    char* zone = alloc((size_t)N_QKV * D_MODEL * 2 +
                       (size_t)D_MODEL * D_MODEL * 2 +
                       (size_t)ROWS * N_QKV * 4 + 8192);
    uint16_t* Wqkv = (uint16_t*)zone;
    uint16_t* Wo   = Wqkv + (size_t)N_QKV * D_MODEL;
    float*    qkv  = (float*)(Wo + (size_t)D_MODEL * D_MODEL);
    // prep buffers alias Wqkv (dead after QKV GEMM): Q 8.39 + K 2.10 + V 2.10
    // = 12.58 MB = exactly sizeof(Wqkv).
    uint16_t* Qb = Wqkv;
    uint16_t* Kb = Qb + (size_t)BATCH * 16 * SEQ * HD;
    uint16_t* Vt = Kb + (size_t)BATCH * 4 * SEQ * HD;
    // attention output aliases qkv (dead after preps)
    uint16_t* att = (uint16_t*)qkv;
    // act aliases zone start (Wqkv/Wo/att all dead after O-proj); 23.1 MB
    uint16_t* act = (uint16_t*)zone;

    auto dq = [&](const int* q, const float* s, uint16_t* o,
                  size_t n, int I, int mode) {
        const int n4 = (int)(n / 4);
        dequant_kernel<<<(n4 + 255) / 256, 256, 0, stream>>>(q, s, o, n4, I, mode);
    };
    dq(wq_q, wq_s, Wqkv, (size_t)2048 * 2048, 2048, 0);
    dq(wk_q, wk_s, Wqkv + (size_t)2048 * 2048, (size_t)512 * 2048, 2048, 0);
    dq(wv_q, wv_s, Wqkv + (size_t)2560 * 2048, (size_t)512 * 2048, 2048, 0);
    dq(wo_q, wo_s, Wo, (size_t)2048 * 2048, 2048, 0);
    dq(gate_q, gate_s, Wgu, (size_t)D_FF * 2048, 2048, 1);
    dq(up_q, up_s, Wgu, (size_t)D_FF * 2048, 2048, 2);
    dq(down_q, down_s, Wdown, (size_t)2048 * D_FF, D_FF, 0);

    biascat_kernel<<<(N_QKV + 255) / 256, 256, 0, stream>>>(bq, bk, bv, bqkv);
    rmsnorm_kernel<<<ROWS, 256, 0, stream>>>(x, w_in, hbuf);

    // QKV: 64x128 tiles -> (2048/64)*(3072/128) = 768 blocks (3/CU)
    gemm_f16_m64_kernel<<<(ROWS / 64) * (N_QKV / 128), 256, 0, stream>>>(
        hbuf, Wqkv, bqkv, nullptr, qkv, ROWS, N_QKV, D_MODEL);

    rope_q_kernel<<<(ROWS * 16 * 64) / 256, 256, 0, stream>>>(qkv, offp, Qb);
    rope_k_kernel<<<(ROWS * 4 * 64) / 256, 256, 0, stream>>>(qkv, offp, Kb);
    prep_v_kernel<<<BATCH * 4 * (SEQ / 64), 256, 0, stream>>>(qkv, Vt);

    attn_kernel<<<BATCH * HEADS * (SEQ / 64), 256, 0, stream>>>(Qb, Kb, Vt, att);

    // O-proj: 512 blocks (2/CU)
    gemm_f16_m64_kernel<<<(ROWS / 64) * (D_MODEL / 128), 256, 0, stream>>>(
        att, Wo, nullptr, x, x2, ROWS, D_MODEL, D_MODEL);

    rmsnorm_kernel<<<ROWS, 256, 0, stream>>>(x2, w_post, hbuf);

    // GU: 128x128 tiles, 1408 blocks (5.5/CU) — healthy at round-6 profile
    gemm_f16_glu_kernel<<<(ROWS / 128) * (2 * D_FF / 128), 256, 0, stream>>>(
        hbuf, Wgu, act, ROWS, 2 * D_FF, D_MODEL);

    // down: 512 blocks (2/CU)
    gemm_f16_m64_kernel<<<(ROWS / 64) * (D_MODEL / 128), 256, 0, stream>>>(
        act, Wdown, nullptr, x2, (float*)d_out, ROWS, D_MODEL, D_FF);
}